// Round 6
// baseline (570.958 us; speedup 1.0000x reference)
//
#include <hip/hip_runtime.h>

#define NA   16384
#define NE   524288
#define NM   256
#define FF   4800
#define HH   512
#define NMX  10
#define NSPH 9

typedef __bf16 bf16x8 __attribute__((ext_vector_type(8)));
typedef float  f32x4  __attribute__((ext_vector_type(4)));
typedef unsigned short u16x8 __attribute__((ext_vector_type(8)));

__device__ inline unsigned short f2bf(float x){
  unsigned int u = __builtin_bit_cast(unsigned int, x);
  u += 0x7fffu + ((u >> 16) & 1u);
  return (unsigned short)(u >> 16);
}
__device__ inline float bf2f(unsigned short h){
  unsigned int u = ((unsigned int)h) << 16;
  return __builtin_bit_cast(float, u);
}
__device__ inline void atomic_add_f(float* p, float v){
  __hip_atomic_fetch_add(p, v, __ATOMIC_RELAXED, __HIP_MEMORY_SCOPE_AGENT);
}
__device__ inline void gload16(const void* g, void* l){
  __builtin_amdgcn_global_load_lds(
      (const __attribute__((address_space(1))) unsigned int*)g,
      (__attribute__((address_space(3))) unsigned int*)l, 16, 0, 0);
}
__device__ inline float silu(float x){ return x / (1.f + __expf(-x)); }

// exclusive block scan (<=4 waves, 256 threads)
__device__ inline int block_scan_excl(int v, int tid, int* lds){
  int lane = tid & 63, w = tid >> 6;
  int x = v;
  #pragma unroll
  for (int d = 1; d < 64; d <<= 1){
    int y = __shfl_up(x, d, 64);
    if (lane >= d) x += y;
  }
  if (lane == 63) lds[w] = x;
  __syncthreads();
  int wsum = 0;
  for (int i = 0; i < w; i++) wsum += lds[i];
  return wsum + x - v;
}

// ---------------- edge counting sort by key = recv*4 + species(sender) ----------------
__global__ __launch_bounds__(256) void k_hist(const int* __restrict__ ei,
                                              const int* __restrict__ numbers,
                                              int* __restrict__ cnt64k){
  int e = blockIdx.x * 256 + threadIdx.x;
  if (e < NE){
    int key = ei[NE + e] * 4 + numbers[ei[e]];
    atomicAdd(&cnt64k[key], 1);
  }
}

// hierarchical scan of 65536 bins: A) per-block sums, B) scan 256 sums, C) per-bin starts
__global__ __launch_bounds__(256) void k_scanA(const int* __restrict__ cnt64k,
                                               int* __restrict__ bsum){
  __shared__ int lds[4];
  int tid = threadIdx.x;
  int v = cnt64k[blockIdx.x * 256 + tid];
  int lane = tid & 63;
  #pragma unroll
  for (int m = 32; m; m >>= 1) v += __shfl_xor(v, m, 64);
  if (lane == 0) lds[tid >> 6] = v;
  __syncthreads();
  if (tid == 0) bsum[blockIdx.x] = lds[0] + lds[1] + lds[2] + lds[3];
}

__global__ __launch_bounds__(256) void k_scanB(const int* __restrict__ bsum,
                                               int* __restrict__ boff, int* __restrict__ starts){
  __shared__ int lds[4];
  int tid = threadIdx.x;
  int v = bsum[tid];
  int e = block_scan_excl(v, tid, lds);
  boff[tid] = e;
  if (tid == 0) starts[65536] = NE;
}

__global__ __launch_bounds__(256) void k_scanC(const int* __restrict__ cnt64k,
                                               const int* __restrict__ boff,
                                               int* __restrict__ starts, int* __restrict__ cursor){
  __shared__ int lds[4];
  int tid = threadIdx.x;
  int bin = blockIdx.x * 256 + tid;
  int v = cnt64k[bin];
  int e = block_scan_excl(v, tid, lds) + boff[blockIdx.x];
  starts[bin] = e;
  cursor[bin] = e;
}

__global__ __launch_bounds__(256) void k_sortperm(const int* __restrict__ ei,
                                                  const int* __restrict__ numbers,
                                                  int* __restrict__ cursor, int* __restrict__ perm){
  int e = blockIdx.x * 256 + threadIdx.x;
  if (e < NE){
    int key = ei[NE + e] * 4 + numbers[ei[e]];
    int p = atomicAdd(&cursor[key], 1);
    perm[p] = e;
  }
}

// ---------------- species grouping of atoms ----------------
__global__ void k_count(const int* __restrict__ numbers, int* __restrict__ cnt){
  int i = blockIdx.x * 256 + threadIdx.x;
  if (i < NA) atomicAdd(&cnt[numbers[i]], 1);
}
__global__ void k_offs(const int* __restrict__ cnt, int* __restrict__ offs){
  if (threadIdx.x == 0){
    int o = 0;
    for (int s = 0; s < 4; s++){ offs[s] = o; o += cnt[s]; }
    offs[4] = o;
  }
}
__global__ void k_scatter(const int* __restrict__ numbers, const int* __restrict__ offs,
                          int* __restrict__ cursor, int* __restrict__ list){
  int i = blockIdx.x * 256 + threadIdx.x;
  if (i < NA){
    int s = numbers[i];
    int p = atomicAdd(&cursor[s], 1);
    list[offs[s] + p] = i;
  }
}

// ---------------- fused per-atom: edge accum -> U-mix -> ps (PERMUTED layout) + stats --
// ps layout: f' = l*1600 + q*40 + p  (l-uniform waves, bf16x8 stores)
__global__ __launch_bounds__(384) void k_atom(
    const float* __restrict__ pos, const float* __restrict__ cells,
    const int* __restrict__ ei, const float* __restrict__ eoff,
    const int* __restrict__ batch, const int* __restrict__ startsK,
    const int* __restrict__ perm, const float* __restrict__ U,
    unsigned short* __restrict__ ps, float* __restrict__ stats)
{
  __shared__ float Rl[64][NMX];
  __shared__ float Yl[64][NSPH];
  __shared__ float csr[360];
  __shared__ float cl[360];
  __shared__ float red[16];
  __shared__ float ul[16];
  int atom = blockIdx.x;
  int tid = threadIdx.x;
  if (tid < 16) ul[tid] = U[tid];
  int e0 = startsK[atom * 4], e1 = startsK[atom * 4 + 4];
  float px = pos[atom*3+0], py = pos[atom*3+1], pz = pos[atom*3+2];
  int sp = tid / 90, n = (tid % 90) / 9, k = tid % 9;
  int aS = 0, aE = 0;
  if (tid < 360){ aS = startsK[atom * 4 + sp]; aE = startsK[atom * 4 + sp + 1]; }
  float acc = 0.f;
  for (int base = e0; base < e1; base += 64){
    int nch = min(64, e1 - base);
    if (tid < nch){
      int e = perm[base + tid];
      int snd = ei[e];
      const float* C = cells + (size_t)batch[snd] * 9;
      float o0 = eoff[e*3+0], o1 = eoff[e*3+1], o2 = eoff[e*3+2];
      float rx = px - pos[snd*3+0] + o0*C[0] + o1*C[3] + o2*C[6];
      float ry = py - pos[snd*3+1] + o0*C[1] + o1*C[4] + o2*C[7];
      float rz = pz - pos[snd*3+2] + o0*C[2] + o1*C[5] + o2*C[8];
      float r = sqrtf(rx*rx + ry*ry + rz*rz + 1e-12f);
      float inv = 1.f / r;
      float hx = rx*inv, hy = ry*inv, hz = rz*inv;
      float fc = (r < 5.f) ? (0.5f * (__cosf(r * 0.6283185307179586f) + 1.f)) : 0.f;
      #pragma unroll
      for (int nn = 0; nn < NMX; nn++){
        float d = r - (5.f/9.f) * (float)nn;
        Rl[tid][nn] = __expf(-2.f * d * d) * fc;
      }
      Yl[tid][0] = 0.28209479177387814f;
      Yl[tid][1] = 0.4886025119029199f * hy;
      Yl[tid][2] = 0.4886025119029199f * hz;
      Yl[tid][3] = 0.4886025119029199f * hx;
      Yl[tid][4] = 1.0925484305920792f * hx * hy;
      Yl[tid][5] = 1.0925484305920792f * hy * hz;
      Yl[tid][6] = 0.31539156525252005f * (3.f * hz * hz - 1.f);
      Yl[tid][7] = 1.0925484305920792f * hx * hz;
      Yl[tid][8] = 0.5462742152960396f * (hx * hx - hy * hy);
    }
    __syncthreads();
    if (tid < 360){
      int lo2 = max(aS, base), hi2 = min(aE, base + nch);
      for (int e = lo2; e < hi2; e++){
        int j = e - base;
        acc += Rl[j][n] * Yl[j][k];
      }
    }
    __syncthreads();
  }
  if (tid < 360) csr[tid] = acc;
  __syncthreads();
  if (tid < 360){
    int a = tid / 90, nk = tid % 90;
    cl[tid] = ul[a*4+0]*csr[nk] + ul[a*4+1]*csr[90+nk]
            + ul[a*4+2]*csr[180+nk] + ul[a*4+3]*csr[270+nk];
  }
  __syncthreads();
  float s1 = 0.f, s2 = 0.f;
  // 600 chunks of 8: chunk c -> l = c/200, m = (c%200)*8 .. +8, f' = l*1600 + m
  for (int chunk = tid; chunk < 600; chunk += 384){
    int l = (chunk >= 400) ? 2 : ((chunk >= 200) ? 1 : 0);
    int m0 = (chunk - l * 200) * 8;
    unsigned short o[8];
    #pragma unroll
    for (int j = 0; j < 8; j++){
      int m = m0 + j;
      int q = m / 40, p = m - q * 40;
      const float* cq = &cl[q * 9];
      const float* cp = &cl[p * 9];
      float v;
      if (l == 0)      v = cq[0]*cp[0];
      else if (l == 1) v = (cq[1]*cp[1] + cq[2]*cp[2] + cq[3]*cp[3]) * 0.5773502691896258f;
      else             v = (cq[4]*cp[4] + cq[5]*cp[5] + cq[6]*cp[6] + cq[7]*cp[7] + cq[8]*cp[8]) * 0.4472135954999579f;
      o[j] = f2bf(v);
      s1 += v; s2 += v * v;
    }
    *reinterpret_cast<u16x8*>(ps + (size_t)atom * FF + chunk * 8) = *(const u16x8*)o;
  }
  #pragma unroll
  for (int m = 32; m; m >>= 1){ s1 += __shfl_xor(s1, m, 64); s2 += __shfl_xor(s2, m, 64); }
  int w = tid >> 6, lane = tid & 63;
  if (lane == 0){ red[w] = s1; red[8 + w] = s2; }
  __syncthreads();
  if (tid == 0){
    float t1 = 0.f, t2 = 0.f;
    for (int i = 0; i < 6; i++){ t1 += red[i]; t2 += red[8 + i]; }
    float mean = t1 * (1.f / FF);
    float var = t2 * (1.f / FF) - mean * mean;
    var = fmaxf(var, 0.f);
    stats[2*atom]   = mean;
    stats[2*atom+1] = rsqrtf(var + 1e-5f);
  }
}

// ---------------- weight prep (K permuted to match ps: f' = l*1600+q*40+p) ------------
__global__ __launch_bounds__(256) void k_wg1(
    const float* __restrict__ W1, const float* __restrict__ U,
    const float* __restrict__ gamma, const float* __restrict__ beta,
    unsigned short* __restrict__ Wg, float* __restrict__ gW, float* __restrict__ bW)
{
  __shared__ float tg[64][65];
  __shared__ float tb[64][65];
  int n0 = blockIdx.x * 64, f0 = blockIdx.y * 64, s = blockIdx.z;
  int l = blockIdx.y / 25;              // 25 f'-blocks of 64 per l
  float u0 = U[s], u1 = U[4+s], u2 = U[8+s], u3 = U[12+s];
  int tid = threadIdx.x;
  #pragma unroll 4
  for (int rep = 0; rep < 16; rep++){
    int idx = rep * 256 + tid;
    int fi = idx >> 6, ni = idx & 63;
    int fp = f0 + fi;                   // permuted index
    int fsrc = 3 * (fp - 1600 * l) + l; // original index
    size_t base = (size_t)fsrc * 512 + (n0 + ni);
    float w = u0*W1[base] + u1*W1[base + (size_t)FF*512]
            + u2*W1[base + (size_t)2*FF*512] + u3*W1[base + (size_t)3*FF*512];
    tg[fi][ni] = gamma[fsrc] * w;
    tb[fi][ni] = beta[fsrc] * w;
  }
  __syncthreads();
  #pragma unroll 4
  for (int rep = 0; rep < 16; rep++){
    int idx = rep * 256 + tid;
    int ni = idx >> 6, fi = idx & 63;
    Wg[((size_t)s * 512 + n0 + ni) * FF + f0 + fi] = f2bf(tg[fi][ni]);
  }
  if (tid < 64){
    float sg = 0.f, sb = 0.f;
    for (int fi = 0; fi < 64; fi++){ sg += tg[fi][tid]; sb += tb[fi][tid]; }
    atomic_add_f(&gW[s * 512 + n0 + tid], sg);
    atomic_add_f(&bW[s * 512 + n0 + tid], sb);
  }
}

__global__ __launch_bounds__(256) void k_w2t(
    const float* __restrict__ W2, const float* __restrict__ U,
    unsigned short* __restrict__ W2t)
{
  __shared__ float t[64][65];
  int n0 = blockIdx.x * 64, k0 = blockIdx.y * 64, s = blockIdx.z;
  float u0 = U[s], u1 = U[4+s], u2 = U[8+s], u3 = U[12+s];
  int tid = threadIdx.x;
  #pragma unroll 4
  for (int rep = 0; rep < 16; rep++){
    int idx = rep * 256 + tid;
    int ki = idx >> 6, ni = idx & 63;
    size_t base = (size_t)(k0 + ki) * 512 + (n0 + ni);
    t[ki][ni] = u0*W2[base] + u1*W2[base + 512*512]
              + u2*W2[base + 2*512*512] + u3*W2[base + 3*512*512];
  }
  __syncthreads();
  #pragma unroll 4
  for (int rep = 0; rep < 16; rep++){
    int idx = rep * 256 + tid;
    int ni = idx >> 6, ki = idx & 63;
    W2t[((size_t)s * 512 + n0 + ni) * 512 + k0 + ki] = f2bf(t[ki][ni]);
  }
}

__global__ void k_w3(const float* __restrict__ W3, const float* __restrict__ U,
                     float* __restrict__ W3s)
{
  int idx = blockIdx.x * 256 + threadIdx.x;
  if (idx < 4 * 512){
    int s = idx >> 9, k = idx & 511;
    W3s[idx] = U[s]*W3[k] + U[4+s]*W3[512+k] + U[8+s]*W3[2*512+k] + U[12+s]*W3[3*512+k];
  }
}

// ---------------- GEMM template (128x128 tile, BK=64, bf16 MFMA) ----------------
template<int EPI, int NSPLIT>
__global__ __launch_bounds__(256) void k_gemm(
    const unsigned short* __restrict__ Ag, int lda, int K,
    const unsigned short* __restrict__ Btg,
    const int* __restrict__ list, const int* __restrict__ offs, const int* __restrict__ cnt,
    unsigned short* __restrict__ pout,
    const float* __restrict__ W3s, float* __restrict__ pacc)
{
  __shared__ alignas(16) char smem[32768];
  const int NV = 4 * NSPLIT;
  int b = blockIdx.x;
  int y = (b & 7) + 8 * (b / (8 * NV));
  int v = (b >> 3) % NV;
  int x = v & 3, kh = v >> 2;

  int s = 0, t = y;
  for (; s < 4; s++){
    int nts = (cnt[s] + 127) >> 7;
    if (t < nts) break;
    t -= nts;
  }
  if (s >= 4) return;
  int cntS = cnt[s], offS = offs[s];
  int rt = t, n0 = x * 128;
  int tid = threadIdx.x, w = tid >> 6, lane = tid & 63;
  int wr = w >> 1, wc = w & 1;

  const unsigned short* Bts = Btg + (size_t)s * 512 * K;
  const unsigned short* gA[4];
  const unsigned short* gB[4];
  char* lA[4];
  char* lB[4];
  #pragma unroll
  for (int it = 0; it < 4; it++){
    int g = it * 4 + w;
    int idx = g * 64 + lane;
    int row = idx >> 3, ch = idx & 7;
    int cg = ch ^ (row & 7);
    int gr = rt * 128 + row; gr = gr < cntS ? gr : cntS - 1;
    int atom = list[offS + gr];
    gA[it] = Ag + (size_t)atom * lda + cg * 8;
    lA[it] = smem + g * 1024;
    gB[it] = Bts + (size_t)(n0 + row) * K + cg * 8;
    lB[it] = smem + 16384 + g * 1024;
  }

  int hi = lane >> 4, lo = lane & 15;
  f32x4 acc[4][4];
  #pragma unroll
  for (int mi = 0; mi < 4; mi++)
    #pragma unroll
    for (int ni = 0; ni < 4; ni++)
      #pragma unroll
      for (int r = 0; r < 4; r++) acc[mi][ni][r] = 0.f;

  int abase[4], a7[4], bbase[4], b7[4];
  #pragma unroll
  for (int mi = 0; mi < 4; mi++){ int row = wr*64 + mi*16 + lo; abase[mi] = row*128; a7[mi] = row & 7; }
  #pragma unroll
  for (int ni = 0; ni < 4; ni++){ int row = wc*64 + ni*16 + lo; bbase[ni] = 16384 + row*128; b7[ni] = row & 7; }

  int nk = K / 64;
  int k0 = ((nk * kh) / NSPLIT) * 64;
  int k1 = ((nk * (kh + 1)) / NSPLIT) * 64;

  for (int kt = k0; kt < k1; kt += 64){
    #pragma unroll
    for (int it = 0; it < 4; it++) gload16(gA[it] + kt, lA[it]);
    #pragma unroll
    for (int it = 0; it < 4; it++) gload16(gB[it] + kt, lB[it]);
    __syncthreads();
    #pragma unroll
    for (int kk = 0; kk < 2; kk++){
      bf16x8 af[4], bfr[4];
      #pragma unroll
      for (int mi = 0; mi < 4; mi++)
        af[mi] = *(const bf16x8*)(smem + abase[mi] + (((kk*4 + hi) ^ a7[mi]) << 4));
      #pragma unroll
      for (int ni = 0; ni < 4; ni++)
        bfr[ni] = *(const bf16x8*)(smem + bbase[ni] + (((kk*4 + hi) ^ b7[ni]) << 4));
      #pragma unroll
      for (int mi = 0; mi < 4; mi++)
        #pragma unroll
        for (int ni = 0; ni < 4; ni++)
          acc[mi][ni] = __builtin_amdgcn_mfma_f32_16x16x32_bf16(af[mi], bfr[ni], acc[mi][ni], 0, 0, 0);
    }
    __syncthreads();
  }

  int gn[4];
  #pragma unroll
  for (int ni = 0; ni < 4; ni++) gn[ni] = n0 + wc*64 + ni*16 + lo;

  if (EPI == 0){
    #pragma unroll
    for (int mi = 0; mi < 4; mi++){
      #pragma unroll
      for (int j = 0; j < 4; j++){
        int gr = rt*128 + wr*64 + mi*16 + hi*4 + j;
        if (gr < cntS){
          int atom = list[offS + gr];
          #pragma unroll
          for (int ni = 0; ni < 4; ni++)
            pout[((size_t)kh * NA + atom) * 512 + gn[ni]] = f2bf(acc[mi][ni][j]);
        }
      }
    }
  } else {
    float w3v[4];
    #pragma unroll
    for (int ni = 0; ni < 4; ni++) w3v[ni] = W3s[s * 512 + gn[ni]];
    float* pslot = pacc + (size_t)(x * 2 + wc) * NA;
    #pragma unroll
    for (int mi = 0; mi < 4; mi++){
      #pragma unroll
      for (int j = 0; j < 4; j++){
        int gr = rt*128 + wr*64 + mi*16 + hi*4 + j;
        if (gr < cntS){
          int atom = list[offS + gr];
          float pdot = 0.f;
          #pragma unroll
          for (int ni = 0; ni < 4; ni++)
            pdot += silu(acc[mi][ni][j]) * w3v[ni];
          pdot += __shfl_xor(pdot, 1, 16);
          pdot += __shfl_xor(pdot, 2, 16);
          pdot += __shfl_xor(pdot, 4, 16);
          pdot += __shfl_xor(pdot, 8, 16);
          if (lo == 0) pslot[atom] = pdot;
        }
      }
    }
  }
}

// ---------------- epilogue: combine split-K partials + LN-affine + silu -> h1 ---------
__global__ __launch_bounds__(256) void k_epi(
    const unsigned short* __restrict__ pbuf, const float* __restrict__ stats,
    const float* __restrict__ gW, const float* __restrict__ bW,
    const int* __restrict__ numbers, unsigned short* __restrict__ h1)
{
  int w = threadIdx.x >> 6, lane = threadIdx.x & 63;
  int atom = blockIdx.x * 4 + w;
  int s = numbers[atom];
  float mean = stats[2*atom], rstd = stats[2*atom+1];
  int c0 = lane * 8;
  u16x8 a0 = *reinterpret_cast<const u16x8*>(pbuf + (size_t)atom * 512 + c0);
  u16x8 a1 = *reinterpret_cast<const u16x8*>(pbuf + (size_t)(NA + atom) * 512 + c0);
  unsigned short o[8];
  #pragma unroll
  for (int j = 0; j < 8; j++){
    int c = c0 + j;
    float acc = bf2f(a0[j]) + bf2f(a1[j]);
    float vv = rstd * acc + bW[s*512 + c] - mean * rstd * gW[s*512 + c];
    o[j] = f2bf(silu(vv));
  }
  *reinterpret_cast<u16x8*>(h1 + (size_t)atom * 512 + c0) = *(const u16x8*)o;
}

// ---------------- final: sum 8 pacc partials/atom, wave-uniform molecule atomic -------
__global__ __launch_bounds__(256) void k_final2(
    const float* __restrict__ pacc, const int* __restrict__ numbers,
    const int* __restrict__ batch, const float* __restrict__ Wc,
    float* __restrict__ molOut)
{
  int atom = blockIdx.x * 256 + threadIdx.x;
  int lane = threadIdx.x & 63;
  float sum = 0.f;
  #pragma unroll
  for (int p = 0; p < 8; p++) sum += pacc[(size_t)p * NA + atom];
  float val = sum * (1.f / 128.f) + Wc[numbers[atom]];
  int mol = batch[atom];
  int m0 = __shfl(mol, 0, 64);
  int m63 = __shfl(mol, 63, 64);
  if (m0 == m63){
    #pragma unroll
    for (int m = 32; m; m >>= 1) val += __shfl_xor(val, m, 64);
    if (lane == 0) atomic_add_f(&molOut[mol], val);
  } else {
    atomic_add_f(&molOut[mol], val);
  }
}

extern "C" void kernel_launch(void* const* d_in, const int* in_sizes, int n_in,
                              void* d_out, int out_size, void* d_ws, size_t ws_size,
                              hipStream_t stream)
{
  const float* pos     = (const float*)d_in[0];
  const float* cells   = (const float*)d_in[1];
  const int*   numbers = (const int*)d_in[2];
  const int*   ei      = (const int*)d_in[3];
  const float* eoff    = (const float*)d_in[4];
  const int*   batch   = (const int*)d_in[5];
  const float* U       = (const float*)d_in[6];
  const float* gamma   = (const float*)d_in[7];
  const float* beta    = (const float*)d_in[8];
  const float* W1      = (const float*)d_in[9];
  const float* W2      = (const float*)d_in[10];
  const float* W3      = (const float*)d_in[11];
  const float* Wc      = (const float*)d_in[12];
  float* out = (float*)d_out;

  char* ws = (char*)d_ws;
  size_t off = 0;
  auto alloc = [&](size_t bytes) -> void* {
    void* p = ws + off;
    off += (bytes + 255) & ~(size_t)255;
    return p;
  };
  unsigned short* ps   = (unsigned short*)alloc((size_t)NA * FF * 2);      // 157 MB
  unsigned short* pbuf = (unsigned short*)alloc((size_t)2 * NA * 512 * 2); // 32 MB
  float* stats         = (float*)alloc((size_t)NA * 2 * 4);
  unsigned short* Wg1  = (unsigned short*)alloc((size_t)4 * 512 * FF * 2); // 19.7 MB
  float* gW            = (float*)alloc(4 * 512 * 4);
  float* bW            = (float*)alloc(4 * 512 * 4);
  unsigned short* W2t  = (unsigned short*)alloc((size_t)4 * 512 * 512 * 2);
  float* W3s           = (float*)alloc(4 * 512 * 4);
  unsigned short* h1   = (unsigned short*)alloc((size_t)NA * 512 * 2);
  float* pacc          = (float*)alloc((size_t)8 * NA * 4);                // 512 KB
  int* list            = (int*)alloc(NA * 4);
  int* perm            = (int*)alloc((size_t)NE * 4);
  int* startsK         = (int*)alloc((65536 + 1) * 4);
  int* cnt64k          = (int*)alloc(65536 * 4);
  int* cursor64k       = (int*)alloc(65536 * 4);
  int* bsum            = (int*)alloc(256 * 4);
  int* boff            = (int*)alloc(256 * 4);
  int* ints            = (int*)alloc(64);
  int* cnt = ints; int* cursor = ints + 4; int* offs = ints + 8;

  hipMemsetAsync(ints, 0, 64, stream);
  hipMemsetAsync(cnt64k, 0, 65536 * 4, stream);
  hipMemsetAsync(gW, 0, 4 * 512 * 4, stream);
  hipMemsetAsync(bW, 0, 4 * 512 * 4, stream);
  hipMemsetAsync(out, 0, (size_t)out_size * 4, stream);

  // edge counting sort by (recv, sender-species)
  k_hist<<<NE / 256, 256, 0, stream>>>(ei, numbers, cnt64k);
  k_scanA<<<256, 256, 0, stream>>>(cnt64k, bsum);
  k_scanB<<<1, 256, 0, stream>>>(bsum, boff, startsK);
  k_scanC<<<256, 256, 0, stream>>>(cnt64k, boff, startsK, cursor64k);
  k_sortperm<<<NE / 256, 256, 0, stream>>>(ei, numbers, cursor64k, perm);

  // atom species grouping
  k_count<<<NA / 256, 256, 0, stream>>>(numbers, cnt);
  k_offs<<<1, 64, 0, stream>>>(cnt, offs);
  k_scatter<<<NA / 256, 256, 0, stream>>>(numbers, offs, cursor, list);

  // fused edge-accumulate + U-mix + power spectrum + LN stats
  k_atom<<<NA, 384, 0, stream>>>(pos, cells, ei, eoff, batch, startsK, perm, U, ps, stats);

  // weight prep
  k_wg1<<<dim3(8, 75, 4), 256, 0, stream>>>(W1, U, gamma, beta, Wg1, gW, bW);
  k_w2t<<<dim3(8, 8, 4), 256, 0, stream>>>(W2, U, W2t);
  k_w3<<<8, 256, 0, stream>>>(W3, U, W3s);

  // GEMM1 split-K=2 (1088 blocks, XCD-colocated), then LN+silu epilogue
  k_gemm<0, 2><<<1088, 256, 0, stream>>>(ps, FF, FF, Wg1, list, offs, cnt,
                                         pbuf, nullptr, nullptr);
  k_epi<<<NA / 4, 256, 0, stream>>>(pbuf, stats, gW, bW, numbers, h1);

  // GEMM2 with fused silu + W3 dot -> per-atom partials (atomic-free)
  k_gemm<2, 1><<<544, 256, 0, stream>>>(h1, 512, 512, W2t, list, offs, cnt,
                                        nullptr, W3s, pacc);
  k_final2<<<NA / 256, 256, 0, stream>>>(pacc, numbers, batch, Wc, out);
}

// Round 7
// 569.068 us; speedup vs baseline: 1.0033x; 1.0033x over previous
//
#include <hip/hip_runtime.h>

#define NA   16384
#define NE   524288
#define NM   256
#define FF   4800
#define HH   512
#define NMX  10
#define NSPH 9

typedef __bf16 bf16x8 __attribute__((ext_vector_type(8)));
typedef float  f32x4  __attribute__((ext_vector_type(4)));
typedef unsigned short u16x8 __attribute__((ext_vector_type(8)));

__device__ inline unsigned short f2bf(float x){
  unsigned int u = __builtin_bit_cast(unsigned int, x);
  u += 0x7fffu + ((u >> 16) & 1u);
  return (unsigned short)(u >> 16);
}
__device__ inline float bf2f(unsigned short h){
  unsigned int u = ((unsigned int)h) << 16;
  return __builtin_bit_cast(float, u);
}
__device__ inline void atomic_add_f(float* p, float v){
  __hip_atomic_fetch_add(p, v, __ATOMIC_RELAXED, __HIP_MEMORY_SCOPE_AGENT);
}
__device__ inline void gload16(const void* g, void* l){
  __builtin_amdgcn_global_load_lds(
      (const __attribute__((address_space(1))) unsigned int*)g,
      (__attribute__((address_space(3))) unsigned int*)l, 16, 0, 0);
}
__device__ inline float silu(float x){ return x / (1.f + __expf(-x)); }

// exclusive block scan (<=4 waves, 256 threads)
__device__ inline int block_scan_excl(int v, int tid, int* lds){
  int lane = tid & 63, w = tid >> 6;
  int x = v;
  #pragma unroll
  for (int d = 1; d < 64; d <<= 1){
    int y = __shfl_up(x, d, 64);
    if (lane >= d) x += y;
  }
  if (lane == 63) lds[w] = x;
  __syncthreads();
  int wsum = 0;
  for (int i = 0; i < w; i++) wsum += lds[i];
  return wsum + x - v;
}

// ---------------- edge counting sort by key = recv*4 + species(sender) ----------------
__global__ __launch_bounds__(256) void k_hist(const int* __restrict__ ei,
                                              const int* __restrict__ numbers,
                                              int* __restrict__ cnt64k){
  int e = blockIdx.x * 256 + threadIdx.x;
  if (e < NE){
    int key = ei[NE + e] * 4 + numbers[ei[e]];
    atomicAdd(&cnt64k[key], 1);
  }
}

// hierarchical scan of 65536 bins: A) per-block sums, B) scan 256 sums, C) per-bin starts
__global__ __launch_bounds__(256) void k_scanA(const int* __restrict__ cnt64k,
                                               int* __restrict__ bsum){
  __shared__ int lds[4];
  int tid = threadIdx.x;
  int v = cnt64k[blockIdx.x * 256 + tid];
  int lane = tid & 63;
  #pragma unroll
  for (int m = 32; m; m >>= 1) v += __shfl_xor(v, m, 64);
  if (lane == 0) lds[tid >> 6] = v;
  __syncthreads();
  if (tid == 0) bsum[blockIdx.x] = lds[0] + lds[1] + lds[2] + lds[3];
}

__global__ __launch_bounds__(256) void k_scanB(const int* __restrict__ bsum,
                                               int* __restrict__ boff, int* __restrict__ starts){
  __shared__ int lds[4];
  int tid = threadIdx.x;
  int v = bsum[tid];
  int e = block_scan_excl(v, tid, lds);
  boff[tid] = e;
  if (tid == 0) starts[65536] = NE;
}

__global__ __launch_bounds__(256) void k_scanC(const int* __restrict__ cnt64k,
                                               const int* __restrict__ boff,
                                               int* __restrict__ starts, int* __restrict__ cursor){
  __shared__ int lds[4];
  int tid = threadIdx.x;
  int bin = blockIdx.x * 256 + tid;
  int v = cnt64k[bin];
  int e = block_scan_excl(v, tid, lds) + boff[blockIdx.x];
  starts[bin] = e;
  cursor[bin] = e;
}

__global__ __launch_bounds__(256) void k_sortperm(const int* __restrict__ ei,
                                                  const int* __restrict__ numbers,
                                                  int* __restrict__ cursor, int* __restrict__ perm){
  int e = blockIdx.x * 256 + threadIdx.x;
  if (e < NE){
    int key = ei[NE + e] * 4 + numbers[ei[e]];
    int p = atomicAdd(&cursor[key], 1);
    perm[p] = e;
  }
}

// ---------------- species grouping of atoms ----------------
__global__ void k_count(const int* __restrict__ numbers, int* __restrict__ cnt){
  int i = blockIdx.x * 256 + threadIdx.x;
  if (i < NA) atomicAdd(&cnt[numbers[i]], 1);
}
__global__ void k_offs(const int* __restrict__ cnt, int* __restrict__ offs){
  if (threadIdx.x == 0){
    int o = 0;
    for (int s = 0; s < 4; s++){ offs[s] = o; o += cnt[s]; }
    offs[4] = o;
  }
}
__global__ void k_scatter(const int* __restrict__ numbers, const int* __restrict__ offs,
                          int* __restrict__ cursor, int* __restrict__ list){
  int i = blockIdx.x * 256 + threadIdx.x;
  if (i < NA){
    int s = numbers[i];
    int p = atomicAdd(&cursor[s], 1);
    list[offs[s] + p] = i;
  }
}

// ---------------- fused per-atom: edge accum -> U-mix -> ps (PERMUTED layout) + stats --
// ps layout: f' = l*1600 + q*40 + p  (l-uniform waves, bf16x8 stores)
__global__ __launch_bounds__(384) void k_atom(
    const float* __restrict__ pos, const float* __restrict__ cells,
    const int* __restrict__ ei, const float* __restrict__ eoff,
    const int* __restrict__ batch, const int* __restrict__ startsK,
    const int* __restrict__ perm, const float* __restrict__ U,
    unsigned short* __restrict__ ps, float* __restrict__ stats)
{
  __shared__ float Rl[64][NMX];
  __shared__ float Yl[64][NSPH];
  __shared__ float csr[360];
  __shared__ float cl[360];
  __shared__ float red[16];
  __shared__ float ul[16];
  int atom = blockIdx.x;
  int tid = threadIdx.x;
  if (tid < 16) ul[tid] = U[tid];
  int e0 = startsK[atom * 4], e1 = startsK[atom * 4 + 4];
  float px = pos[atom*3+0], py = pos[atom*3+1], pz = pos[atom*3+2];
  int sp = tid / 90, n = (tid % 90) / 9, k = tid % 9;
  int aS = 0, aE = 0;
  if (tid < 360){ aS = startsK[atom * 4 + sp]; aE = startsK[atom * 4 + sp + 1]; }
  float acc = 0.f;
  for (int base = e0; base < e1; base += 64){
    int nch = min(64, e1 - base);
    if (tid < nch){
      int e = perm[base + tid];
      int snd = ei[e];
      const float* C = cells + (size_t)batch[snd] * 9;
      float o0 = eoff[e*3+0], o1 = eoff[e*3+1], o2 = eoff[e*3+2];
      float rx = px - pos[snd*3+0] + o0*C[0] + o1*C[3] + o2*C[6];
      float ry = py - pos[snd*3+1] + o0*C[1] + o1*C[4] + o2*C[7];
      float rz = pz - pos[snd*3+2] + o0*C[2] + o1*C[5] + o2*C[8];
      float r = sqrtf(rx*rx + ry*ry + rz*rz + 1e-12f);
      float inv = 1.f / r;
      float hx = rx*inv, hy = ry*inv, hz = rz*inv;
      float fc = (r < 5.f) ? (0.5f * (__cosf(r * 0.6283185307179586f) + 1.f)) : 0.f;
      #pragma unroll
      for (int nn = 0; nn < NMX; nn++){
        float d = r - (5.f/9.f) * (float)nn;
        Rl[tid][nn] = __expf(-2.f * d * d) * fc;
      }
      Yl[tid][0] = 0.28209479177387814f;
      Yl[tid][1] = 0.4886025119029199f * hy;
      Yl[tid][2] = 0.4886025119029199f * hz;
      Yl[tid][3] = 0.4886025119029199f * hx;
      Yl[tid][4] = 1.0925484305920792f * hx * hy;
      Yl[tid][5] = 1.0925484305920792f * hy * hz;
      Yl[tid][6] = 0.31539156525252005f * (3.f * hz * hz - 1.f);
      Yl[tid][7] = 1.0925484305920792f * hx * hz;
      Yl[tid][8] = 0.5462742152960396f * (hx * hx - hy * hy);
    }
    __syncthreads();
    if (tid < 360){
      int lo2 = max(aS, base), hi2 = min(aE, base + nch);
      for (int e = lo2; e < hi2; e++){
        int j = e - base;
        acc += Rl[j][n] * Yl[j][k];
      }
    }
    __syncthreads();
  }
  if (tid < 360) csr[tid] = acc;
  __syncthreads();
  if (tid < 360){
    int a = tid / 90, nk = tid % 90;
    cl[tid] = ul[a*4+0]*csr[nk] + ul[a*4+1]*csr[90+nk]
            + ul[a*4+2]*csr[180+nk] + ul[a*4+3]*csr[270+nk];
  }
  __syncthreads();
  float s1 = 0.f, s2 = 0.f;
  // 600 chunks of 8: chunk c -> l = c/200, m = (c%200)*8 .. +8, f' = l*1600 + m
  for (int chunk = tid; chunk < 600; chunk += 384){
    int l = (chunk >= 400) ? 2 : ((chunk >= 200) ? 1 : 0);
    int m0 = (chunk - l * 200) * 8;
    unsigned short o[8];
    #pragma unroll
    for (int j = 0; j < 8; j++){
      int m = m0 + j;
      int q = m / 40, p = m - q * 40;
      const float* cq = &cl[q * 9];
      const float* cp = &cl[p * 9];
      float v;
      if (l == 0)      v = cq[0]*cp[0];
      else if (l == 1) v = (cq[1]*cp[1] + cq[2]*cp[2] + cq[3]*cp[3]) * 0.5773502691896258f;
      else             v = (cq[4]*cp[4] + cq[5]*cp[5] + cq[6]*cp[6] + cq[7]*cp[7] + cq[8]*cp[8]) * 0.4472135954999579f;
      o[j] = f2bf(v);
      s1 += v; s2 += v * v;
    }
    *reinterpret_cast<u16x8*>(ps + (size_t)atom * FF + chunk * 8) = *(const u16x8*)o;
  }
  #pragma unroll
  for (int m = 32; m; m >>= 1){ s1 += __shfl_xor(s1, m, 64); s2 += __shfl_xor(s2, m, 64); }
  int w = tid >> 6, lane = tid & 63;
  if (lane == 0){ red[w] = s1; red[8 + w] = s2; }
  __syncthreads();
  if (tid == 0){
    float t1 = 0.f, t2 = 0.f;
    for (int i = 0; i < 6; i++){ t1 += red[i]; t2 += red[8 + i]; }
    float mean = t1 * (1.f / FF);
    float var = t2 * (1.f / FF) - mean * mean;
    var = fmaxf(var, 0.f);
    stats[2*atom]   = mean;
    stats[2*atom+1] = rsqrtf(var + 1e-5f);
  }
}

// ---------------- weight prep (K permuted to match ps: f' = l*1600+q*40+p) ------------
__global__ __launch_bounds__(256) void k_wg1(
    const float* __restrict__ W1, const float* __restrict__ U,
    const float* __restrict__ gamma, const float* __restrict__ beta,
    unsigned short* __restrict__ Wg, float* __restrict__ gW, float* __restrict__ bW)
{
  __shared__ float tg[64][65];
  __shared__ float tb[64][65];
  int n0 = blockIdx.x * 64, f0 = blockIdx.y * 64, s = blockIdx.z;
  int l = blockIdx.y / 25;              // 25 f'-blocks of 64 per l
  float u0 = U[s], u1 = U[4+s], u2 = U[8+s], u3 = U[12+s];
  int tid = threadIdx.x;
  #pragma unroll 4
  for (int rep = 0; rep < 16; rep++){
    int idx = rep * 256 + tid;
    int fi = idx >> 6, ni = idx & 63;
    int fp = f0 + fi;                   // permuted index
    int fsrc = 3 * (fp - 1600 * l) + l; // original index
    size_t base = (size_t)fsrc * 512 + (n0 + ni);
    float w = u0*W1[base] + u1*W1[base + (size_t)FF*512]
            + u2*W1[base + (size_t)2*FF*512] + u3*W1[base + (size_t)3*FF*512];
    tg[fi][ni] = gamma[fsrc] * w;
    tb[fi][ni] = beta[fsrc] * w;
  }
  __syncthreads();
  #pragma unroll 4
  for (int rep = 0; rep < 16; rep++){
    int idx = rep * 256 + tid;
    int ni = idx >> 6, fi = idx & 63;
    Wg[((size_t)s * 512 + n0 + ni) * FF + f0 + fi] = f2bf(tg[fi][ni]);
  }
  if (tid < 64){
    float sg = 0.f, sb = 0.f;
    for (int fi = 0; fi < 64; fi++){ sg += tg[fi][tid]; sb += tb[fi][tid]; }
    atomic_add_f(&gW[s * 512 + n0 + tid], sg);
    atomic_add_f(&bW[s * 512 + n0 + tid], sb);
  }
}

__global__ __launch_bounds__(256) void k_w2t(
    const float* __restrict__ W2, const float* __restrict__ U,
    unsigned short* __restrict__ W2t)
{
  __shared__ float t[64][65];
  int n0 = blockIdx.x * 64, k0 = blockIdx.y * 64, s = blockIdx.z;
  float u0 = U[s], u1 = U[4+s], u2 = U[8+s], u3 = U[12+s];
  int tid = threadIdx.x;
  #pragma unroll 4
  for (int rep = 0; rep < 16; rep++){
    int idx = rep * 256 + tid;
    int ki = idx >> 6, ni = idx & 63;
    size_t base = (size_t)(k0 + ki) * 512 + (n0 + ni);
    t[ki][ni] = u0*W2[base] + u1*W2[base + 512*512]
              + u2*W2[base + 2*512*512] + u3*W2[base + 3*512*512];
  }
  __syncthreads();
  #pragma unroll 4
  for (int rep = 0; rep < 16; rep++){
    int idx = rep * 256 + tid;
    int ni = idx >> 6, ki = idx & 63;
    W2t[((size_t)s * 512 + n0 + ni) * 512 + k0 + ki] = f2bf(t[ki][ni]);
  }
}

__global__ void k_w3(const float* __restrict__ W3, const float* __restrict__ U,
                     float* __restrict__ W3s)
{
  int idx = blockIdx.x * 256 + threadIdx.x;
  if (idx < 4 * 512){
    int s = idx >> 9, k = idx & 511;
    W3s[idx] = U[s]*W3[k] + U[4+s]*W3[512+k] + U[8+s]*W3[2*512+k] + U[12+s]*W3[3*512+k];
  }
}

// ---------------- GEMM template (128x128 tile, BK=64, bf16 MFMA) ----------------
template<int EPI, int NSPLIT>
__global__ __launch_bounds__(256) void k_gemm(
    const unsigned short* __restrict__ Ag, int lda, int K,
    const unsigned short* __restrict__ Btg,
    const int* __restrict__ list, const int* __restrict__ offs, const int* __restrict__ cnt,
    unsigned short* __restrict__ pout,
    const float* __restrict__ W3s, float* __restrict__ pacc)
{
  __shared__ alignas(16) char smem[32768];
  const int NV = 4 * NSPLIT;
  int b = blockIdx.x;
  int y = (b & 7) + 8 * (b / (8 * NV));
  int v = (b >> 3) % NV;
  int x = v & 3, kh = v >> 2;

  int s = 0, t = y;
  for (; s < 4; s++){
    int nts = (cnt[s] + 127) >> 7;
    if (t < nts) break;
    t -= nts;
  }
  if (s >= 4) return;
  int cntS = cnt[s], offS = offs[s];
  int rt = t, n0 = x * 128;
  int tid = threadIdx.x, w = tid >> 6, lane = tid & 63;
  int wr = w >> 1, wc = w & 1;

  const unsigned short* Bts = Btg + (size_t)s * 512 * K;
  const unsigned short* gA[4];
  const unsigned short* gB[4];
  char* lA[4];
  char* lB[4];
  #pragma unroll
  for (int it = 0; it < 4; it++){
    int g = it * 4 + w;
    int idx = g * 64 + lane;
    int row = idx >> 3, ch = idx & 7;
    int cg = ch ^ (row & 7);
    int gr = rt * 128 + row; gr = gr < cntS ? gr : cntS - 1;
    int atom = list[offS + gr];
    gA[it] = Ag + (size_t)atom * lda + cg * 8;
    lA[it] = smem + g * 1024;
    gB[it] = Bts + (size_t)(n0 + row) * K + cg * 8;
    lB[it] = smem + 16384 + g * 1024;
  }

  int hi = lane >> 4, lo = lane & 15;
  f32x4 acc[4][4];
  #pragma unroll
  for (int mi = 0; mi < 4; mi++)
    #pragma unroll
    for (int ni = 0; ni < 4; ni++)
      #pragma unroll
      for (int r = 0; r < 4; r++) acc[mi][ni][r] = 0.f;

  int abase[4], a7[4], bbase[4], b7[4];
  #pragma unroll
  for (int mi = 0; mi < 4; mi++){ int row = wr*64 + mi*16 + lo; abase[mi] = row*128; a7[mi] = row & 7; }
  #pragma unroll
  for (int ni = 0; ni < 4; ni++){ int row = wc*64 + ni*16 + lo; bbase[ni] = 16384 + row*128; b7[ni] = row & 7; }

  int nk = K / 64;
  int k0 = ((nk * kh) / NSPLIT) * 64;
  int k1 = ((nk * (kh + 1)) / NSPLIT) * 64;

  for (int kt = k0; kt < k1; kt += 64){
    #pragma unroll
    for (int it = 0; it < 4; it++) gload16(gA[it] + kt, lA[it]);
    #pragma unroll
    for (int it = 0; it < 4; it++) gload16(gB[it] + kt, lB[it]);
    __syncthreads();
    #pragma unroll
    for (int kk = 0; kk < 2; kk++){
      bf16x8 af[4], bfr[4];
      #pragma unroll
      for (int mi = 0; mi < 4; mi++)
        af[mi] = *(const bf16x8*)(smem + abase[mi] + (((kk*4 + hi) ^ a7[mi]) << 4));
      #pragma unroll
      for (int ni = 0; ni < 4; ni++)
        bfr[ni] = *(const bf16x8*)(smem + bbase[ni] + (((kk*4 + hi) ^ b7[ni]) << 4));
      #pragma unroll
      for (int mi = 0; mi < 4; mi++)
        #pragma unroll
        for (int ni = 0; ni < 4; ni++)
          acc[mi][ni] = __builtin_amdgcn_mfma_f32_16x16x32_bf16(af[mi], bfr[ni], acc[mi][ni], 0, 0, 0);
    }
    __syncthreads();
  }

  int gn[4];
  #pragma unroll
  for (int ni = 0; ni < 4; ni++) gn[ni] = n0 + wc*64 + ni*16 + lo;

  if (EPI == 0){
    #pragma unroll
    for (int mi = 0; mi < 4; mi++){
      #pragma unroll
      for (int j = 0; j < 4; j++){
        int gr = rt*128 + wr*64 + mi*16 + hi*4 + j;
        if (gr < cntS){
          int atom = list[offS + gr];
          #pragma unroll
          for (int ni = 0; ni < 4; ni++)
            pout[((size_t)kh * NA + atom) * 512 + gn[ni]] = f2bf(acc[mi][ni][j]);
        }
      }
    }
  } else {
    float w3v[4];
    #pragma unroll
    for (int ni = 0; ni < 4; ni++) w3v[ni] = W3s[s * 512 + gn[ni]];
    float* pslot = pacc + (size_t)(x * 2 + wc) * NA;
    #pragma unroll
    for (int mi = 0; mi < 4; mi++){
      #pragma unroll
      for (int j = 0; j < 4; j++){
        int gr = rt*128 + wr*64 + mi*16 + hi*4 + j;
        if (gr < cntS){
          int atom = list[offS + gr];
          float pdot = 0.f;
          #pragma unroll
          for (int ni = 0; ni < 4; ni++)
            pdot += silu(acc[mi][ni][j]) * w3v[ni];
          pdot += __shfl_xor(pdot, 1, 16);
          pdot += __shfl_xor(pdot, 2, 16);
          pdot += __shfl_xor(pdot, 4, 16);
          pdot += __shfl_xor(pdot, 8, 16);
          if (lo == 0) pslot[atom] = pdot;
        }
      }
    }
  }
}

// ---------------- epilogue: combine split-K partials + LN-affine + silu -> h1 ---------
__global__ __launch_bounds__(256) void k_epi(
    const unsigned short* __restrict__ pbuf, const float* __restrict__ stats,
    const float* __restrict__ gW, const float* __restrict__ bW,
    const int* __restrict__ numbers, unsigned short* __restrict__ h1)
{
  int w = threadIdx.x >> 6, lane = threadIdx.x & 63;
  int atom = blockIdx.x * 4 + w;
  int s = numbers[atom];
  float mean = stats[2*atom], rstd = stats[2*atom+1];
  int c0 = lane * 8;
  u16x8 a0 = *reinterpret_cast<const u16x8*>(pbuf + (size_t)atom * 512 + c0);
  u16x8 a1 = *reinterpret_cast<const u16x8*>(pbuf + (size_t)(NA + atom) * 512 + c0);
  unsigned short o[8];
  #pragma unroll
  for (int j = 0; j < 8; j++){
    int c = c0 + j;
    float acc = bf2f(a0[j]) + bf2f(a1[j]);
    float vv = rstd * acc + bW[s*512 + c] - mean * rstd * gW[s*512 + c];
    o[j] = f2bf(silu(vv));
  }
  *reinterpret_cast<u16x8*>(h1 + (size_t)atom * 512 + c0) = *(const u16x8*)o;
}

// ---------------- final: sum 8 pacc partials/atom, wave-uniform molecule atomic -------
__global__ __launch_bounds__(256) void k_final2(
    const float* __restrict__ pacc, const int* __restrict__ numbers,
    const int* __restrict__ batch, const float* __restrict__ Wc,
    float* __restrict__ molOut)
{
  int atom = blockIdx.x * 256 + threadIdx.x;
  int lane = threadIdx.x & 63;
  float sum = 0.f;
  #pragma unroll
  for (int p = 0; p < 8; p++) sum += pacc[(size_t)p * NA + atom];
  float val = sum * (1.f / 128.f) + Wc[numbers[atom]];
  int mol = batch[atom];
  int m0 = __shfl(mol, 0, 64);
  int m63 = __shfl(mol, 63, 64);
  if (m0 == m63){
    #pragma unroll
    for (int m = 32; m; m >>= 1) val += __shfl_xor(val, m, 64);
    if (lane == 0) atomic_add_f(&molOut[mol], val);
  } else {
    atomic_add_f(&molOut[mol], val);
  }
}

extern "C" void kernel_launch(void* const* d_in, const int* in_sizes, int n_in,
                              void* d_out, int out_size, void* d_ws, size_t ws_size,
                              hipStream_t stream)
{
  const float* pos     = (const float*)d_in[0];
  const float* cells   = (const float*)d_in[1];
  const int*   numbers = (const int*)d_in[2];
  const int*   ei      = (const int*)d_in[3];
  const float* eoff    = (const float*)d_in[4];
  const int*   batch   = (const int*)d_in[5];
  const float* U       = (const float*)d_in[6];
  const float* gamma   = (const float*)d_in[7];
  const float* beta    = (const float*)d_in[8];
  const float* W1      = (const float*)d_in[9];
  const float* W2      = (const float*)d_in[10];
  const float* W3      = (const float*)d_in[11];
  const float* Wc      = (const float*)d_in[12];
  float* out = (float*)d_out;

  char* ws = (char*)d_ws;
  size_t off = 0;
  auto alloc = [&](size_t bytes) -> void* {
    void* p = ws + off;
    off += (bytes + 255) & ~(size_t)255;
    return p;
  };
  unsigned short* ps   = (unsigned short*)alloc((size_t)NA * FF * 2);      // 157 MB
  unsigned short* pbuf = (unsigned short*)alloc((size_t)2 * NA * 512 * 2); // 32 MB
  float* stats         = (float*)alloc((size_t)NA * 2 * 4);
  unsigned short* Wg1  = (unsigned short*)alloc((size_t)4 * 512 * FF * 2); // 19.7 MB
  float* gW            = (float*)alloc(4 * 512 * 4);
  float* bW            = (float*)alloc(4 * 512 * 4);
  unsigned short* W2t  = (unsigned short*)alloc((size_t)4 * 512 * 512 * 2);
  float* W3s           = (float*)alloc(4 * 512 * 4);
  unsigned short* h1   = (unsigned short*)alloc((size_t)NA * 512 * 2);
  float* pacc          = (float*)alloc((size_t)8 * NA * 4);                // 512 KB
  int* list            = (int*)alloc(NA * 4);
  int* perm            = (int*)alloc((size_t)NE * 4);
  int* startsK         = (int*)alloc((65536 + 1) * 4);
  int* cnt64k          = (int*)alloc(65536 * 4);
  int* cursor64k       = (int*)alloc(65536 * 4);
  int* bsum            = (int*)alloc(256 * 4);
  int* boff            = (int*)alloc(256 * 4);
  int* ints            = (int*)alloc(64);
  int* cnt = ints; int* cursor = ints + 4; int* offs = ints + 8;

  hipMemsetAsync(ints, 0, 64, stream);
  hipMemsetAsync(cnt64k, 0, 65536 * 4, stream);
  hipMemsetAsync(gW, 0, 4 * 512 * 4, stream);
  hipMemsetAsync(bW, 0, 4 * 512 * 4, stream);
  hipMemsetAsync(out, 0, (size_t)out_size * 4, stream);

  // edge counting sort by (recv, sender-species)
  k_hist<<<NE / 256, 256, 0, stream>>>(ei, numbers, cnt64k);
  k_scanA<<<256, 256, 0, stream>>>(cnt64k, bsum);
  k_scanB<<<1, 256, 0, stream>>>(bsum, boff, startsK);
  k_scanC<<<256, 256, 0, stream>>>(cnt64k, boff, startsK, cursor64k);
  k_sortperm<<<NE / 256, 256, 0, stream>>>(ei, numbers, cursor64k, perm);

  // atom species grouping
  k_count<<<NA / 256, 256, 0, stream>>>(numbers, cnt);
  k_offs<<<1, 64, 0, stream>>>(cnt, offs);
  k_scatter<<<NA / 256, 256, 0, stream>>>(numbers, offs, cursor, list);

  // fused edge-accumulate + U-mix + power spectrum + LN stats
  k_atom<<<NA, 384, 0, stream>>>(pos, cells, ei, eoff, batch, startsK, perm, U, ps, stats);

  // weight prep
  k_wg1<<<dim3(8, 75, 4), 256, 0, stream>>>(W1, U, gamma, beta, Wg1, gW, bW);
  k_w2t<<<dim3(8, 8, 4), 256, 0, stream>>>(W2, U, W2t);
  k_w3<<<8, 256, 0, stream>>>(W3, U, W3s);

  // GEMM1 split-K=2 (1088 blocks, XCD-colocated), then LN+silu epilogue
  k_gemm<0, 2><<<1088, 256, 0, stream>>>(ps, FF, FF, Wg1, list, offs, cnt,
                                         pbuf, nullptr, nullptr);
  k_epi<<<NA / 4, 256, 0, stream>>>(pbuf, stats, gW, bW, numbers, h1);

  // GEMM2 with fused silu + W3 dot -> per-atom partials (atomic-free)
  k_gemm<2, 1><<<544, 256, 0, stream>>>(h1, 512, 512, W2t, list, offs, cnt,
                                        nullptr, W3s, pacc);
  k_final2<<<NA / 256, 256, 0, stream>>>(pacc, numbers, batch, Wc, out);
}

// Round 8
// 523.593 us; speedup vs baseline: 1.0905x; 1.0869x over previous
//
#include <hip/hip_runtime.h>

#define NA   16384
#define NE   524288
#define NM   256
#define FF   4800
#define FR   2496   // folded K: 3 * 832
#define FL   832    // per-l stride (820 pairs + 12 pad)
#define NPAIR 820
#define HH   512
#define NMX  10
#define NSPH 9

typedef __bf16 bf16x8 __attribute__((ext_vector_type(8)));
typedef float  f32x4  __attribute__((ext_vector_type(4)));
typedef unsigned short u16x8 __attribute__((ext_vector_type(8)));

__device__ inline unsigned short f2bf(float x){
  unsigned int u = __builtin_bit_cast(unsigned int, x);
  u += 0x7fffu + ((u >> 16) & 1u);
  return (unsigned short)(u >> 16);
}
__device__ inline float bf2f(unsigned short h){
  unsigned int u = ((unsigned int)h) << 16;
  return __builtin_bit_cast(float, u);
}
__device__ inline void atomic_add_f(float* p, float v){
  __hip_atomic_fetch_add(p, v, __ATOMIC_RELAXED, __HIP_MEMORY_SCOPE_AGENT);
}
__device__ inline void gload16(const void* g, void* l){
  __builtin_amdgcn_global_load_lds(
      (const __attribute__((address_space(1))) unsigned int*)g,
      (__attribute__((address_space(3))) unsigned int*)l, 16, 0, 0);
}
__device__ inline float silu(float x){ return x / (1.f + __expf(-x)); }

// build upper-triangular pair table: m -> (q<<8)|p, q<=p<40, 820 entries
__device__ inline void build_qp(unsigned short* qp, int tid){
  if (tid < 40){
    int q = tid;
    int m0 = q * 40 - (q * (q - 1)) / 2;
    for (int p = q; p < 40; p++) qp[m0 + p - q] = (unsigned short)((q << 8) | p);
  }
}

// exclusive block scan (<=4 waves, 256 threads)
__device__ inline int block_scan_excl(int v, int tid, int* lds){
  int lane = tid & 63, w = tid >> 6;
  int x = v;
  #pragma unroll
  for (int d = 1; d < 64; d <<= 1){
    int y = __shfl_up(x, d, 64);
    if (lane >= d) x += y;
  }
  if (lane == 63) lds[w] = x;
  __syncthreads();
  int wsum = 0;
  for (int i = 0; i < w; i++) wsum += lds[i];
  return wsum + x - v;
}

// ---------------- edge counting sort by key = recv*4 + species(sender) ----------------
__global__ __launch_bounds__(256) void k_hist(const int* __restrict__ ei,
                                              const int* __restrict__ numbers,
                                              int* __restrict__ cnt64k){
  int e = blockIdx.x * 256 + threadIdx.x;
  if (e < NE){
    int key = ei[NE + e] * 4 + numbers[ei[e]];
    atomicAdd(&cnt64k[key], 1);
  }
}

__global__ __launch_bounds__(256) void k_scanA(const int* __restrict__ cnt64k,
                                               int* __restrict__ bsum){
  __shared__ int lds[4];
  int tid = threadIdx.x;
  int v = cnt64k[blockIdx.x * 256 + tid];
  int lane = tid & 63;
  #pragma unroll
  for (int m = 32; m; m >>= 1) v += __shfl_xor(v, m, 64);
  if (lane == 0) lds[tid >> 6] = v;
  __syncthreads();
  if (tid == 0) bsum[blockIdx.x] = lds[0] + lds[1] + lds[2] + lds[3];
}

__global__ __launch_bounds__(256) void k_scanB(const int* __restrict__ bsum,
                                               int* __restrict__ boff, int* __restrict__ starts){
  __shared__ int lds[4];
  int tid = threadIdx.x;
  int v = bsum[tid];
  int e = block_scan_excl(v, tid, lds);
  boff[tid] = e;
  if (tid == 0) starts[65536] = NE;
}

__global__ __launch_bounds__(256) void k_scanC(const int* __restrict__ cnt64k,
                                               const int* __restrict__ boff,
                                               int* __restrict__ starts, int* __restrict__ cursor){
  __shared__ int lds[4];
  int tid = threadIdx.x;
  int bin = blockIdx.x * 256 + tid;
  int v = cnt64k[bin];
  int e = block_scan_excl(v, tid, lds) + boff[blockIdx.x];
  starts[bin] = e;
  cursor[bin] = e;
}

__global__ __launch_bounds__(256) void k_sortperm(const int* __restrict__ ei,
                                                  const int* __restrict__ numbers,
                                                  int* __restrict__ cursor, int* __restrict__ perm){
  int e = blockIdx.x * 256 + threadIdx.x;
  if (e < NE){
    int key = ei[NE + e] * 4 + numbers[ei[e]];
    int p = atomicAdd(&cursor[key], 1);
    perm[p] = e;
  }
}

// ---------------- species grouping of atoms ----------------
__global__ void k_count(const int* __restrict__ numbers, int* __restrict__ cnt){
  int i = blockIdx.x * 256 + threadIdx.x;
  if (i < NA) atomicAdd(&cnt[numbers[i]], 1);
}
__global__ void k_offs(const int* __restrict__ cnt, int* __restrict__ offs){
  if (threadIdx.x == 0){
    int o = 0;
    for (int s = 0; s < 4; s++){ offs[s] = o; o += cnt[s]; }
    offs[4] = o;
  }
}
__global__ void k_scatter(const int* __restrict__ numbers, const int* __restrict__ offs,
                          int* __restrict__ cursor, int* __restrict__ list){
  int i = blockIdx.x * 256 + threadIdx.x;
  if (i < NA){
    int s = numbers[i];
    int p = atomicAdd(&cursor[s], 1);
    list[offs[s] + p] = i;
  }
}

// ---------------- fused per-atom: edge accum -> U-mix -> FOLDED ps + weighted stats ---
// ps layout: f' = l*832 + m, m indexes unordered pairs q<=p (820 + 12 zero pad)
__global__ __launch_bounds__(384) void k_atom(
    const float* __restrict__ pos, const float* __restrict__ cells,
    const int* __restrict__ ei, const float* __restrict__ eoff,
    const int* __restrict__ batch, const int* __restrict__ startsK,
    const int* __restrict__ perm, const float* __restrict__ U,
    unsigned short* __restrict__ ps, float* __restrict__ stats)
{
  __shared__ float Rl[64][NMX];
  __shared__ float Yl[64][NSPH];
  __shared__ float csr[360];
  __shared__ float cl[360];
  __shared__ float red[16];
  __shared__ float ul[16];
  __shared__ unsigned short qp[NPAIR];
  int atom = blockIdx.x;
  int tid = threadIdx.x;
  if (tid < 16) ul[tid] = U[tid];
  build_qp(qp, tid);
  int e0 = startsK[atom * 4], e1 = startsK[atom * 4 + 4];
  float px = pos[atom*3+0], py = pos[atom*3+1], pz = pos[atom*3+2];
  int sp = tid / 90, n = (tid % 90) / 9, k = tid % 9;
  int aS = 0, aE = 0;
  if (tid < 360){ aS = startsK[atom * 4 + sp]; aE = startsK[atom * 4 + sp + 1]; }
  float acc = 0.f;
  for (int base = e0; base < e1; base += 64){
    int nch = min(64, e1 - base);
    if (tid < nch){
      int e = perm[base + tid];
      int snd = ei[e];
      const float* C = cells + (size_t)batch[snd] * 9;
      float o0 = eoff[e*3+0], o1 = eoff[e*3+1], o2 = eoff[e*3+2];
      float rx = px - pos[snd*3+0] + o0*C[0] + o1*C[3] + o2*C[6];
      float ry = py - pos[snd*3+1] + o0*C[1] + o1*C[4] + o2*C[7];
      float rz = pz - pos[snd*3+2] + o0*C[2] + o1*C[5] + o2*C[8];
      float r = sqrtf(rx*rx + ry*ry + rz*rz + 1e-12f);
      float inv = 1.f / r;
      float hx = rx*inv, hy = ry*inv, hz = rz*inv;
      float fc = (r < 5.f) ? (0.5f * (__cosf(r * 0.6283185307179586f) + 1.f)) : 0.f;
      #pragma unroll
      for (int nn = 0; nn < NMX; nn++){
        float d = r - (5.f/9.f) * (float)nn;
        Rl[tid][nn] = __expf(-2.f * d * d) * fc;
      }
      Yl[tid][0] = 0.28209479177387814f;
      Yl[tid][1] = 0.4886025119029199f * hy;
      Yl[tid][2] = 0.4886025119029199f * hz;
      Yl[tid][3] = 0.4886025119029199f * hx;
      Yl[tid][4] = 1.0925484305920792f * hx * hy;
      Yl[tid][5] = 1.0925484305920792f * hy * hz;
      Yl[tid][6] = 0.31539156525252005f * (3.f * hz * hz - 1.f);
      Yl[tid][7] = 1.0925484305920792f * hx * hz;
      Yl[tid][8] = 0.5462742152960396f * (hx * hx - hy * hy);
    }
    __syncthreads();
    if (tid < 360){
      int lo2 = max(aS, base), hi2 = min(aE, base + nch);
      for (int e = lo2; e < hi2; e++){
        int j = e - base;
        acc += Rl[j][n] * Yl[j][k];
      }
    }
    __syncthreads();
  }
  if (tid < 360) csr[tid] = acc;
  __syncthreads();
  if (tid < 360){
    int a = tid / 90, nk = tid % 90;
    cl[tid] = ul[a*4+0]*csr[nk] + ul[a*4+1]*csr[90+nk]
            + ul[a*4+2]*csr[180+nk] + ul[a*4+3]*csr[270+nk];
  }
  __syncthreads();
  float s1 = 0.f, s2 = 0.f;
  // 312 chunks of 8: chunk c -> l = c/104, m = (c%104)*8 .. +8, f' = l*832 + m
  if (tid < 312){
    int chunk = tid;
    int l = (chunk >= 208) ? 2 : ((chunk >= 104) ? 1 : 0);
    int m0 = (chunk - l * 104) * 8;
    unsigned short o[8];
    #pragma unroll
    for (int j = 0; j < 8; j++){
      int m = m0 + j;
      float v = 0.f, wgt = 0.f;
      if (m < NPAIR){
        int q = qp[m] >> 8, p = qp[m] & 255;
        const float* cq = &cl[q * 9];
        const float* cp = &cl[p * 9];
        if (l == 0)      v = cq[0]*cp[0];
        else if (l == 1) v = (cq[1]*cp[1] + cq[2]*cp[2] + cq[3]*cp[3]) * 0.5773502691896258f;
        else             v = (cq[4]*cp[4] + cq[5]*cp[5] + cq[6]*cp[6] + cq[7]*cp[7] + cq[8]*cp[8]) * 0.4472135954999579f;
        wgt = (p != q) ? 2.f : 1.f;
      }
      o[j] = f2bf(v);
      s1 += wgt * v; s2 += wgt * v * v;
    }
    *reinterpret_cast<u16x8*>(ps + (size_t)atom * FR + chunk * 8) = *(const u16x8*)o;
  }
  #pragma unroll
  for (int m = 32; m; m >>= 1){ s1 += __shfl_xor(s1, m, 64); s2 += __shfl_xor(s2, m, 64); }
  int w = tid >> 6, lane = tid & 63;
  if (lane == 0){ red[w] = s1; red[8 + w] = s2; }
  __syncthreads();
  if (tid == 0){
    float t1 = 0.f, t2 = 0.f;
    for (int i = 0; i < 6; i++){ t1 += red[i]; t2 += red[8 + i]; }
    float mean = t1 * (1.f / FF);
    float var = t2 * (1.f / FF) - mean * mean;
    var = fmaxf(var, 0.f);
    stats[2*atom]   = mean;
    stats[2*atom+1] = rsqrtf(var + 1e-5f);
  }
}

// ---------------- weight prep: FOLDED Wg[s][n][f'], f' = l*832 + pair m ---------------
// Wg = gamma_qp*W_qp + (q!=p) gamma_pq*W_pq ; pads zero. gW/bW full-F column sums.
__global__ __launch_bounds__(256) void k_wg1(
    const float* __restrict__ W1, const float* __restrict__ U,
    const float* __restrict__ gamma, const float* __restrict__ beta,
    unsigned short* __restrict__ Wg, float* __restrict__ gW, float* __restrict__ bW)
{
  __shared__ float tg[64][65];
  __shared__ float tb[64][65];
  __shared__ unsigned short qp[NPAIR];
  int n0 = blockIdx.x * 64, f0 = blockIdx.y * 64, s = blockIdx.z;
  int l = blockIdx.y / 13;               // 13 f'-blocks of 64 per l (832/64)
  int mblk = (blockIdx.y - l * 13) * 64;
  float u0 = U[s], u1 = U[4+s], u2 = U[8+s], u3 = U[12+s];
  int tid = threadIdx.x;
  build_qp(qp, tid);
  __syncthreads();
  #pragma unroll 4
  for (int rep = 0; rep < 16; rep++){
    int idx = rep * 256 + tid;
    int fi = idx >> 6, ni = idx & 63;
    int m = mblk + fi;
    float tgv = 0.f, tbv = 0.f;
    if (m < NPAIR){
      int q = qp[m] >> 8, p = qp[m] & 255;
      int fa = (q * 40 + p) * 3 + l;
      size_t basea = (size_t)fa * 512 + (n0 + ni);
      float wa = u0*W1[basea] + u1*W1[basea + (size_t)FF*512]
               + u2*W1[basea + (size_t)2*FF*512] + u3*W1[basea + (size_t)3*FF*512];
      tgv = gamma[fa] * wa;
      tbv = beta[fa] * wa;
      if (p != q){
        int fb = (p * 40 + q) * 3 + l;
        size_t baseb = (size_t)fb * 512 + (n0 + ni);
        float wb = u0*W1[baseb] + u1*W1[baseb + (size_t)FF*512]
                 + u2*W1[baseb + (size_t)2*FF*512] + u3*W1[baseb + (size_t)3*FF*512];
        tgv += gamma[fb] * wb;
        tbv += beta[fb] * wb;
      }
    }
    tg[fi][ni] = tgv;
    tb[fi][ni] = tbv;
  }
  __syncthreads();
  #pragma unroll 4
  for (int rep = 0; rep < 16; rep++){
    int idx = rep * 256 + tid;
    int ni = idx >> 6, fi = idx & 63;
    Wg[((size_t)s * 512 + n0 + ni) * FR + f0 + fi] = f2bf(tg[fi][ni]);
  }
  if (tid < 64){
    float sg = 0.f, sb = 0.f;
    for (int fi = 0; fi < 64; fi++){ sg += tg[fi][tid]; sb += tb[fi][tid]; }
    atomic_add_f(&gW[s * 512 + n0 + tid], sg);
    atomic_add_f(&bW[s * 512 + n0 + tid], sb);
  }
}

__global__ __launch_bounds__(256) void k_w2t(
    const float* __restrict__ W2, const float* __restrict__ U,
    unsigned short* __restrict__ W2t)
{
  __shared__ float t[64][65];
  int n0 = blockIdx.x * 64, k0 = blockIdx.y * 64, s = blockIdx.z;
  float u0 = U[s], u1 = U[4+s], u2 = U[8+s], u3 = U[12+s];
  int tid = threadIdx.x;
  #pragma unroll 4
  for (int rep = 0; rep < 16; rep++){
    int idx = rep * 256 + tid;
    int ki = idx >> 6, ni = idx & 63;
    size_t base = (size_t)(k0 + ki) * 512 + (n0 + ni);
    t[ki][ni] = u0*W2[base] + u1*W2[base + 512*512]
              + u2*W2[base + 2*512*512] + u3*W2[base + 3*512*512];
  }
  __syncthreads();
  #pragma unroll 4
  for (int rep = 0; rep < 16; rep++){
    int idx = rep * 256 + tid;
    int ni = idx >> 6, ki = idx & 63;
    W2t[((size_t)s * 512 + n0 + ni) * 512 + k0 + ki] = f2bf(t[ki][ni]);
  }
}

__global__ void k_w3(const float* __restrict__ W3, const float* __restrict__ U,
                     float* __restrict__ W3s)
{
  int idx = blockIdx.x * 256 + threadIdx.x;
  if (idx < 4 * 512){
    int s = idx >> 9, k = idx & 511;
    W3s[idx] = U[s]*W3[k] + U[4+s]*W3[512+k] + U[8+s]*W3[2*512+k] + U[12+s]*W3[3*512+k];
  }
}

// ---------------- GEMM template (128x128 tile, BK=64, bf16 MFMA) ----------------
template<int EPI, int NSPLIT>
__global__ __launch_bounds__(256) void k_gemm(
    const unsigned short* __restrict__ Ag, int lda, int K,
    const unsigned short* __restrict__ Btg,
    const int* __restrict__ list, const int* __restrict__ offs, const int* __restrict__ cnt,
    unsigned short* __restrict__ pout,
    const float* __restrict__ W3s, float* __restrict__ pacc)
{
  __shared__ alignas(16) char smem[32768];
  const int NV = 4 * NSPLIT;
  int b = blockIdx.x;
  int y = (b & 7) + 8 * (b / (8 * NV));
  int v = (b >> 3) % NV;
  int x = v & 3, kh = v >> 2;

  int s = 0, t = y;
  for (; s < 4; s++){
    int nts = (cnt[s] + 127) >> 7;
    if (t < nts) break;
    t -= nts;
  }
  if (s >= 4) return;
  int cntS = cnt[s], offS = offs[s];
  int rt = t, n0 = x * 128;
  int tid = threadIdx.x, w = tid >> 6, lane = tid & 63;
  int wr = w >> 1, wc = w & 1;

  const unsigned short* Bts = Btg + (size_t)s * 512 * K;
  const unsigned short* gA[4];
  const unsigned short* gB[4];
  char* lA[4];
  char* lB[4];
  #pragma unroll
  for (int it = 0; it < 4; it++){
    int g = it * 4 + w;
    int idx = g * 64 + lane;
    int row = idx >> 3, ch = idx & 7;
    int cg = ch ^ (row & 7);
    int gr = rt * 128 + row; gr = gr < cntS ? gr : cntS - 1;
    int atom = list[offS + gr];
    gA[it] = Ag + (size_t)atom * lda + cg * 8;
    lA[it] = smem + g * 1024;
    gB[it] = Bts + (size_t)(n0 + row) * K + cg * 8;
    lB[it] = smem + 16384 + g * 1024;
  }

  int hi = lane >> 4, lo = lane & 15;
  f32x4 acc[4][4];
  #pragma unroll
  for (int mi = 0; mi < 4; mi++)
    #pragma unroll
    for (int ni = 0; ni < 4; ni++)
      #pragma unroll
      for (int r = 0; r < 4; r++) acc[mi][ni][r] = 0.f;

  int abase[4], a7[4], bbase[4], b7[4];
  #pragma unroll
  for (int mi = 0; mi < 4; mi++){ int row = wr*64 + mi*16 + lo; abase[mi] = row*128; a7[mi] = row & 7; }
  #pragma unroll
  for (int ni = 0; ni < 4; ni++){ int row = wc*64 + ni*16 + lo; bbase[ni] = 16384 + row*128; b7[ni] = row & 7; }

  int nk = K / 64;
  int k0 = ((nk * kh) / NSPLIT) * 64;
  int k1 = ((nk * (kh + 1)) / NSPLIT) * 64;

  for (int kt = k0; kt < k1; kt += 64){
    #pragma unroll
    for (int it = 0; it < 4; it++) gload16(gA[it] + kt, lA[it]);
    #pragma unroll
    for (int it = 0; it < 4; it++) gload16(gB[it] + kt, lB[it]);
    __syncthreads();
    #pragma unroll
    for (int kk = 0; kk < 2; kk++){
      bf16x8 af[4], bfr[4];
      #pragma unroll
      for (int mi = 0; mi < 4; mi++)
        af[mi] = *(const bf16x8*)(smem + abase[mi] + (((kk*4 + hi) ^ a7[mi]) << 4));
      #pragma unroll
      for (int ni = 0; ni < 4; ni++)
        bfr[ni] = *(const bf16x8*)(smem + bbase[ni] + (((kk*4 + hi) ^ b7[ni]) << 4));
      #pragma unroll
      for (int mi = 0; mi < 4; mi++)
        #pragma unroll
        for (int ni = 0; ni < 4; ni++)
          acc[mi][ni] = __builtin_amdgcn_mfma_f32_16x16x32_bf16(af[mi], bfr[ni], acc[mi][ni], 0, 0, 0);
    }
    __syncthreads();
  }

  int gn[4];
  #pragma unroll
  for (int ni = 0; ni < 4; ni++) gn[ni] = n0 + wc*64 + ni*16 + lo;

  if (EPI == 0){
    #pragma unroll
    for (int mi = 0; mi < 4; mi++){
      #pragma unroll
      for (int j = 0; j < 4; j++){
        int gr = rt*128 + wr*64 + mi*16 + hi*4 + j;
        if (gr < cntS){
          int atom = list[offS + gr];
          #pragma unroll
          for (int ni = 0; ni < 4; ni++)
            pout[((size_t)kh * NA + atom) * 512 + gn[ni]] = f2bf(acc[mi][ni][j]);
        }
      }
    }
  } else {
    float w3v[4];
    #pragma unroll
    for (int ni = 0; ni < 4; ni++) w3v[ni] = W3s[s * 512 + gn[ni]];
    float* pslot = pacc + (size_t)(x * 2 + wc) * NA;
    #pragma unroll
    for (int mi = 0; mi < 4; mi++){
      #pragma unroll
      for (int j = 0; j < 4; j++){
        int gr = rt*128 + wr*64 + mi*16 + hi*4 + j;
        if (gr < cntS){
          int atom = list[offS + gr];
          float pdot = 0.f;
          #pragma unroll
          for (int ni = 0; ni < 4; ni++)
            pdot += silu(acc[mi][ni][j]) * w3v[ni];
          pdot += __shfl_xor(pdot, 1, 16);
          pdot += __shfl_xor(pdot, 2, 16);
          pdot += __shfl_xor(pdot, 4, 16);
          pdot += __shfl_xor(pdot, 8, 16);
          if (lo == 0) pslot[atom] = pdot;
        }
      }
    }
  }
}

// ---------------- epilogue: combine split-K partials + LN-affine + silu -> h1 ---------
__global__ __launch_bounds__(256) void k_epi(
    const unsigned short* __restrict__ pbuf, const float* __restrict__ stats,
    const float* __restrict__ gW, const float* __restrict__ bW,
    const int* __restrict__ numbers, unsigned short* __restrict__ h1)
{
  int w = threadIdx.x >> 6, lane = threadIdx.x & 63;
  int atom = blockIdx.x * 4 + w;
  int s = numbers[atom];
  float mean = stats[2*atom], rstd = stats[2*atom+1];
  int c0 = lane * 8;
  u16x8 a0 = *reinterpret_cast<const u16x8*>(pbuf + (size_t)atom * 512 + c0);
  u16x8 a1 = *reinterpret_cast<const u16x8*>(pbuf + (size_t)(NA + atom) * 512 + c0);
  unsigned short o[8];
  #pragma unroll
  for (int j = 0; j < 8; j++){
    int c = c0 + j;
    float acc = bf2f(a0[j]) + bf2f(a1[j]);
    float vv = rstd * acc + bW[s*512 + c] - mean * rstd * gW[s*512 + c];
    o[j] = f2bf(silu(vv));
  }
  *reinterpret_cast<u16x8*>(h1 + (size_t)atom * 512 + c0) = *(const u16x8*)o;
}

// ---------------- final: sum 8 pacc partials/atom, wave-uniform molecule atomic -------
__global__ __launch_bounds__(256) void k_final2(
    const float* __restrict__ pacc, const int* __restrict__ numbers,
    const int* __restrict__ batch, const float* __restrict__ Wc,
    float* __restrict__ molOut)
{
  int atom = blockIdx.x * 256 + threadIdx.x;
  int lane = threadIdx.x & 63;
  float sum = 0.f;
  #pragma unroll
  for (int p = 0; p < 8; p++) sum += pacc[(size_t)p * NA + atom];
  float val = sum * (1.f / 128.f) + Wc[numbers[atom]];
  int mol = batch[atom];
  int m0 = __shfl(mol, 0, 64);
  int m63 = __shfl(mol, 63, 64);
  if (m0 == m63){
    #pragma unroll
    for (int m = 32; m; m >>= 1) val += __shfl_xor(val, m, 64);
    if (lane == 0) atomic_add_f(&molOut[mol], val);
  } else {
    atomic_add_f(&molOut[mol], val);
  }
}

extern "C" void kernel_launch(void* const* d_in, const int* in_sizes, int n_in,
                              void* d_out, int out_size, void* d_ws, size_t ws_size,
                              hipStream_t stream)
{
  const float* pos     = (const float*)d_in[0];
  const float* cells   = (const float*)d_in[1];
  const int*   numbers = (const int*)d_in[2];
  const int*   ei      = (const int*)d_in[3];
  const float* eoff    = (const float*)d_in[4];
  const int*   batch   = (const int*)d_in[5];
  const float* U       = (const float*)d_in[6];
  const float* gamma   = (const float*)d_in[7];
  const float* beta    = (const float*)d_in[8];
  const float* W1      = (const float*)d_in[9];
  const float* W2      = (const float*)d_in[10];
  const float* W3      = (const float*)d_in[11];
  const float* Wc      = (const float*)d_in[12];
  float* out = (float*)d_out;

  char* ws = (char*)d_ws;
  size_t off = 0;
  auto alloc = [&](size_t bytes) -> void* {
    void* p = ws + off;
    off += (bytes + 255) & ~(size_t)255;
    return p;
  };
  unsigned short* ps   = (unsigned short*)alloc((size_t)NA * FR * 2);      // 78 MB
  unsigned short* pbuf = (unsigned short*)alloc((size_t)2 * NA * 512 * 2); // 32 MB
  float* stats         = (float*)alloc((size_t)NA * 2 * 4);
  unsigned short* Wg1  = (unsigned short*)alloc((size_t)4 * 512 * FR * 2); // 10.2 MB
  float* gW            = (float*)alloc(4 * 512 * 4);
  float* bW            = (float*)alloc(4 * 512 * 4);
  unsigned short* W2t  = (unsigned short*)alloc((size_t)4 * 512 * 512 * 2);
  float* W3s           = (float*)alloc(4 * 512 * 4);
  unsigned short* h1   = (unsigned short*)alloc((size_t)NA * 512 * 2);
  float* pacc          = (float*)alloc((size_t)8 * NA * 4);                // 512 KB
  int* list            = (int*)alloc(NA * 4);
  int* perm            = (int*)alloc((size_t)NE * 4);
  int* startsK         = (int*)alloc((65536 + 1) * 4);
  int* cnt64k          = (int*)alloc(65536 * 4);
  int* cursor64k       = (int*)alloc(65536 * 4);
  int* bsum            = (int*)alloc(256 * 4);
  int* boff            = (int*)alloc(256 * 4);
  int* ints            = (int*)alloc(64);
  int* cnt = ints; int* cursor = ints + 4; int* offs = ints + 8;

  hipMemsetAsync(ints, 0, 64, stream);
  hipMemsetAsync(cnt64k, 0, 65536 * 4, stream);
  hipMemsetAsync(gW, 0, 4 * 512 * 4, stream);
  hipMemsetAsync(bW, 0, 4 * 512 * 4, stream);
  hipMemsetAsync(out, 0, (size_t)out_size * 4, stream);

  // edge counting sort by (recv, sender-species)
  k_hist<<<NE / 256, 256, 0, stream>>>(ei, numbers, cnt64k);
  k_scanA<<<256, 256, 0, stream>>>(cnt64k, bsum);
  k_scanB<<<1, 256, 0, stream>>>(bsum, boff, startsK);
  k_scanC<<<256, 256, 0, stream>>>(cnt64k, boff, startsK, cursor64k);
  k_sortperm<<<NE / 256, 256, 0, stream>>>(ei, numbers, cursor64k, perm);

  // atom species grouping
  k_count<<<NA / 256, 256, 0, stream>>>(numbers, cnt);
  k_offs<<<1, 64, 0, stream>>>(cnt, offs);
  k_scatter<<<NA / 256, 256, 0, stream>>>(numbers, offs, cursor, list);

  // fused edge-accumulate + U-mix + folded power spectrum + LN stats
  k_atom<<<NA, 384, 0, stream>>>(pos, cells, ei, eoff, batch, startsK, perm, U, ps, stats);

  // weight prep (folded K = 2496)
  k_wg1<<<dim3(8, 39, 4), 256, 0, stream>>>(W1, U, gamma, beta, Wg1, gW, bW);
  k_w2t<<<dim3(8, 8, 4), 256, 0, stream>>>(W2, U, W2t);
  k_w3<<<8, 256, 0, stream>>>(W3, U, W3s);

  // GEMM1 split-K=2 (K=2496), then LN+silu epilogue
  k_gemm<0, 2><<<1088, 256, 0, stream>>>(ps, FR, FR, Wg1, list, offs, cnt,
                                         pbuf, nullptr, nullptr);
  k_epi<<<NA / 4, 256, 0, stream>>>(pbuf, stats, gW, bW, numbers, h1);

  // GEMM2 with fused silu + W3 dot -> per-atom partials (atomic-free)
  k_gemm<2, 1><<<544, 256, 0, stream>>>(h1, 512, 512, W2t, list, offs, cnt,
                                        nullptr, W3s, pacc);
  k_final2<<<NA / 256, 256, 0, stream>>>(pacc, numbers, batch, Wc, out);
}

// Round 9
// 334.603 us; speedup vs baseline: 1.7064x; 1.5648x over previous
//
#include <hip/hip_runtime.h>

#define NA   16384
#define NE   524288
#define NM   256
#define FF   4800
#define FR   2496   // folded K: 3 * 832
#define FL   832    // per-l stride (820 pairs + 12 pad)
#define NPAIR 820
#define HH   512
#define NMX  10
#define NSPH 9

typedef __bf16 bf16x8 __attribute__((ext_vector_type(8)));
typedef float  f32x4  __attribute__((ext_vector_type(4)));
typedef unsigned short u16x8 __attribute__((ext_vector_type(8)));

__device__ inline unsigned short f2bf(float x){
  unsigned int u = __builtin_bit_cast(unsigned int, x);
  u += 0x7fffu + ((u >> 16) & 1u);
  return (unsigned short)(u >> 16);
}
__device__ inline float bf2f(unsigned short h){
  unsigned int u = ((unsigned int)h) << 16;
  return __builtin_bit_cast(float, u);
}
__device__ inline void atomic_add_f(float* p, float v){
  __hip_atomic_fetch_add(p, v, __ATOMIC_RELAXED, __HIP_MEMORY_SCOPE_AGENT);
}
__device__ inline void gload16(const void* g, void* l){
  __builtin_amdgcn_global_load_lds(
      (const __attribute__((address_space(1))) unsigned int*)g,
      (__attribute__((address_space(3))) unsigned int*)l, 16, 0, 0);
}
__device__ inline float silu(float x){ return x / (1.f + __expf(-x)); }

// build upper-triangular pair table: m -> (q<<8)|p, q<=p<40, 820 entries
__device__ inline void build_qp(unsigned short* qp, int tid){
  if (tid < 40){
    int q = tid;
    int m0 = q * 40 - (q * (q - 1)) / 2;
    for (int p = q; p < 40; p++) qp[m0 + p - q] = (unsigned short)((q << 8) | p);
  }
}

// exclusive block scan (<=4 waves, 256 threads)
__device__ inline int block_scan_excl(int v, int tid, int* lds){
  int lane = tid & 63, w = tid >> 6;
  int x = v;
  #pragma unroll
  for (int d = 1; d < 64; d <<= 1){
    int y = __shfl_up(x, d, 64);
    if (lane >= d) x += y;
  }
  if (lane == 63) lds[w] = x;
  __syncthreads();
  int wsum = 0;
  for (int i = 0; i < w; i++) wsum += lds[i];
  return wsum + x - v;
}

// ---------------- edge counting sort by key = recv*4 + species(sender) ----------------
__global__ __launch_bounds__(256) void k_hist(const int* __restrict__ ei,
                                              const int* __restrict__ numbers,
                                              int* __restrict__ cnt64k){
  int e = blockIdx.x * 256 + threadIdx.x;
  if (e < NE){
    int key = ei[NE + e] * 4 + numbers[ei[e]];
    atomicAdd(&cnt64k[key], 1);
  }
}

__global__ __launch_bounds__(256) void k_scanA(const int* __restrict__ cnt64k,
                                               int* __restrict__ bsum){
  __shared__ int lds[4];
  int tid = threadIdx.x;
  int v = cnt64k[blockIdx.x * 256 + tid];
  int lane = tid & 63;
  #pragma unroll
  for (int m = 32; m; m >>= 1) v += __shfl_xor(v, m, 64);
  if (lane == 0) lds[tid >> 6] = v;
  __syncthreads();
  if (tid == 0) bsum[blockIdx.x] = lds[0] + lds[1] + lds[2] + lds[3];
}

__global__ __launch_bounds__(256) void k_scanB(const int* __restrict__ bsum,
                                               int* __restrict__ boff, int* __restrict__ starts){
  __shared__ int lds[4];
  int tid = threadIdx.x;
  int v = bsum[tid];
  int e = block_scan_excl(v, tid, lds);
  boff[tid] = e;
  if (tid == 0) starts[65536] = NE;
}

__global__ __launch_bounds__(256) void k_scanC(const int* __restrict__ cnt64k,
                                               const int* __restrict__ boff,
                                               int* __restrict__ starts, int* __restrict__ cursor){
  __shared__ int lds[4];
  int tid = threadIdx.x;
  int bin = blockIdx.x * 256 + tid;
  int v = cnt64k[bin];
  int e = block_scan_excl(v, tid, lds) + boff[blockIdx.x];
  starts[bin] = e;
  cursor[bin] = e;
}

__global__ __launch_bounds__(256) void k_sortperm(const int* __restrict__ ei,
                                                  const int* __restrict__ numbers,
                                                  int* __restrict__ cursor, int* __restrict__ perm){
  int e = blockIdx.x * 256 + threadIdx.x;
  if (e < NE){
    int key = ei[NE + e] * 4 + numbers[ei[e]];
    int p = atomicAdd(&cursor[key], 1);
    perm[p] = e;
  }
}

// ---------------- species grouping of atoms (contention-free counting sort) -----------
__global__ __launch_bounds__(256) void k_acount(const int* __restrict__ numbers,
                                                int* __restrict__ bhist){
  __shared__ int h[4];
  int tid = threadIdx.x;
  if (tid < 4) h[tid] = 0;
  __syncthreads();
  atomicAdd(&h[numbers[blockIdx.x * 256 + tid]], 1);
  __syncthreads();
  if (tid < 4) bhist[blockIdx.x * 4 + tid] = h[tid];
}

__global__ void k_aoffs(const int* __restrict__ bhist, int* __restrict__ boffs,
                        int* __restrict__ ints){
  if (threadIdx.x == 0){
    int* cnt = ints; int* offs = ints + 8;
    int tot[4] = {0,0,0,0};
    for (int b = 0; b < 64; b++)
      for (int s = 0; s < 4; s++) tot[s] += bhist[b*4 + s];
    int o = 0;
    for (int s = 0; s < 4; s++){ cnt[s] = tot[s]; offs[s] = o; o += tot[s]; }
    offs[4] = o;
    int run[4];
    for (int s = 0; s < 4; s++) run[s] = offs[s];
    for (int b = 0; b < 64; b++)
      for (int s = 0; s < 4; s++){ boffs[b*4 + s] = run[s]; run[s] += bhist[b*4 + s]; }
  }
}

__global__ __launch_bounds__(256) void k_aplace(const int* __restrict__ numbers,
                                                const int* __restrict__ boffs,
                                                int* __restrict__ list){
  __shared__ int ws[4][4]; // [wave][species]
  int tid = threadIdx.x, w = tid >> 6, lane = tid & 63;
  int i = blockIdx.x * 256 + tid;
  int sp = numbers[i];
  int rank = 0;
  #pragma unroll
  for (int s = 0; s < 4; s++){
    unsigned long long m = __ballot(sp == s);
    if (s == sp) rank = __popcll(m & (((unsigned long long)1 << lane) - 1));
    if (lane == 0) ws[w][s] = __popcll(m);
  }
  __syncthreads();
  int pre = 0;
  for (int w2 = 0; w2 < w; w2++) pre += ws[w2][sp];
  list[boffs[blockIdx.x * 4 + sp] + pre + rank] = i;
}

// ---------------- fused per-atom: edge accum -> U-mix -> FOLDED ps + weighted stats ---
// ps layout: f' = l*832 + m, m indexes unordered pairs q<=p (820 + 12 zero pad)
__global__ __launch_bounds__(384) void k_atom(
    const float* __restrict__ pos, const float* __restrict__ cells,
    const int* __restrict__ ei, const float* __restrict__ eoff,
    const int* __restrict__ batch, const int* __restrict__ startsK,
    const int* __restrict__ perm, const float* __restrict__ U,
    unsigned short* __restrict__ ps, float* __restrict__ stats)
{
  __shared__ float Rl[64][NMX];
  __shared__ float Yl[64][NSPH];
  __shared__ float csr[360];
  __shared__ float cl[360];
  __shared__ float red[16];
  __shared__ float ul[16];
  __shared__ unsigned short qp[NPAIR];
  int atom = blockIdx.x;
  int tid = threadIdx.x;
  if (tid < 16) ul[tid] = U[tid];
  build_qp(qp, tid);
  int e0 = startsK[atom * 4], e1 = startsK[atom * 4 + 4];
  float px = pos[atom*3+0], py = pos[atom*3+1], pz = pos[atom*3+2];
  int sp = tid / 90, n = (tid % 90) / 9, k = tid % 9;
  int aS = 0, aE = 0;
  if (tid < 360){ aS = startsK[atom * 4 + sp]; aE = startsK[atom * 4 + sp + 1]; }
  float acc = 0.f;
  for (int base = e0; base < e1; base += 64){
    int nch = min(64, e1 - base);
    if (tid < nch){
      int e = perm[base + tid];
      int snd = ei[e];
      const float* C = cells + (size_t)batch[snd] * 9;
      float o0 = eoff[e*3+0], o1 = eoff[e*3+1], o2 = eoff[e*3+2];
      float rx = px - pos[snd*3+0] + o0*C[0] + o1*C[3] + o2*C[6];
      float ry = py - pos[snd*3+1] + o0*C[1] + o1*C[4] + o2*C[7];
      float rz = pz - pos[snd*3+2] + o0*C[2] + o1*C[5] + o2*C[8];
      float r = sqrtf(rx*rx + ry*ry + rz*rz + 1e-12f);
      float inv = 1.f / r;
      float hx = rx*inv, hy = ry*inv, hz = rz*inv;
      float fc = (r < 5.f) ? (0.5f * (__cosf(r * 0.6283185307179586f) + 1.f)) : 0.f;
      #pragma unroll
      for (int nn = 0; nn < NMX; nn++){
        float d = r - (5.f/9.f) * (float)nn;
        Rl[tid][nn] = __expf(-2.f * d * d) * fc;
      }
      Yl[tid][0] = 0.28209479177387814f;
      Yl[tid][1] = 0.4886025119029199f * hy;
      Yl[tid][2] = 0.4886025119029199f * hz;
      Yl[tid][3] = 0.4886025119029199f * hx;
      Yl[tid][4] = 1.0925484305920792f * hx * hy;
      Yl[tid][5] = 1.0925484305920792f * hy * hz;
      Yl[tid][6] = 0.31539156525252005f * (3.f * hz * hz - 1.f);
      Yl[tid][7] = 1.0925484305920792f * hx * hz;
      Yl[tid][8] = 0.5462742152960396f * (hx * hx - hy * hy);
    }
    __syncthreads();
    if (tid < 360){
      int lo2 = max(aS, base), hi2 = min(aE, base + nch);
      for (int e = lo2; e < hi2; e++){
        int j = e - base;
        acc += Rl[j][n] * Yl[j][k];
      }
    }
    __syncthreads();
  }
  if (tid < 360) csr[tid] = acc;
  __syncthreads();
  if (tid < 360){
    int a = tid / 90, nk = tid % 90;
    cl[tid] = ul[a*4+0]*csr[nk] + ul[a*4+1]*csr[90+nk]
            + ul[a*4+2]*csr[180+nk] + ul[a*4+3]*csr[270+nk];
  }
  __syncthreads();
  float s1 = 0.f, s2 = 0.f;
  // 312 chunks of 8: chunk c -> l = c/104, m = (c%104)*8 .. +8, f' = l*832 + m
  if (tid < 312){
    int chunk = tid;
    int l = (chunk >= 208) ? 2 : ((chunk >= 104) ? 1 : 0);
    int m0 = (chunk - l * 104) * 8;
    unsigned short o[8];
    #pragma unroll
    for (int j = 0; j < 8; j++){
      int m = m0 + j;
      float v = 0.f, wgt = 0.f;
      if (m < NPAIR){
        int q = qp[m] >> 8, p = qp[m] & 255;
        const float* cq = &cl[q * 9];
        const float* cp = &cl[p * 9];
        if (l == 0)      v = cq[0]*cp[0];
        else if (l == 1) v = (cq[1]*cp[1] + cq[2]*cp[2] + cq[3]*cp[3]) * 0.5773502691896258f;
        else             v = (cq[4]*cp[4] + cq[5]*cp[5] + cq[6]*cp[6] + cq[7]*cp[7] + cq[8]*cp[8]) * 0.4472135954999579f;
        wgt = (p != q) ? 2.f : 1.f;
      }
      o[j] = f2bf(v);
      s1 += wgt * v; s2 += wgt * v * v;
    }
    *reinterpret_cast<u16x8*>(ps + (size_t)atom * FR + chunk * 8) = *(const u16x8*)o;
  }
  #pragma unroll
  for (int m = 32; m; m >>= 1){ s1 += __shfl_xor(s1, m, 64); s2 += __shfl_xor(s2, m, 64); }
  int w = tid >> 6, lane = tid & 63;
  if (lane == 0){ red[w] = s1; red[8 + w] = s2; }
  __syncthreads();
  if (tid == 0){
    float t1 = 0.f, t2 = 0.f;
    for (int i = 0; i < 6; i++){ t1 += red[i]; t2 += red[8 + i]; }
    float mean = t1 * (1.f / FF);
    float var = t2 * (1.f / FF) - mean * mean;
    var = fmaxf(var, 0.f);
    stats[2*atom]   = mean;
    stats[2*atom+1] = rsqrtf(var + 1e-5f);
  }
}

// ---------------- weight prep: FOLDED Wg[s][n][f'], f' = l*832 + pair m ---------------
__global__ __launch_bounds__(256) void k_wg1(
    const float* __restrict__ W1, const float* __restrict__ U,
    const float* __restrict__ gamma, const float* __restrict__ beta,
    unsigned short* __restrict__ Wg, float* __restrict__ gW, float* __restrict__ bW)
{
  __shared__ float tg[64][65];
  __shared__ float tb[64][65];
  __shared__ unsigned short qp[NPAIR];
  int n0 = blockIdx.x * 64, f0 = blockIdx.y * 64, s = blockIdx.z;
  int l = blockIdx.y / 13;               // 13 f'-blocks of 64 per l (832/64)
  int mblk = (blockIdx.y - l * 13) * 64;
  float u0 = U[s], u1 = U[4+s], u2 = U[8+s], u3 = U[12+s];
  int tid = threadIdx.x;
  build_qp(qp, tid);
  __syncthreads();
  #pragma unroll 4
  for (int rep = 0; rep < 16; rep++){
    int idx = rep * 256 + tid;
    int fi = idx >> 6, ni = idx & 63;
    int m = mblk + fi;
    float tgv = 0.f, tbv = 0.f;
    if (m < NPAIR){
      int q = qp[m] >> 8, p = qp[m] & 255;
      int fa = (q * 40 + p) * 3 + l;
      size_t basea = (size_t)fa * 512 + (n0 + ni);
      float wa = u0*W1[basea] + u1*W1[basea + (size_t)FF*512]
               + u2*W1[basea + (size_t)2*FF*512] + u3*W1[basea + (size_t)3*FF*512];
      tgv = gamma[fa] * wa;
      tbv = beta[fa] * wa;
      if (p != q){
        int fb = (p * 40 + q) * 3 + l;
        size_t baseb = (size_t)fb * 512 + (n0 + ni);
        float wb = u0*W1[baseb] + u1*W1[baseb + (size_t)FF*512]
                 + u2*W1[baseb + (size_t)2*FF*512] + u3*W1[baseb + (size_t)3*FF*512];
        tgv += gamma[fb] * wb;
        tbv += beta[fb] * wb;
      }
    }
    tg[fi][ni] = tgv;
    tb[fi][ni] = tbv;
  }
  __syncthreads();
  #pragma unroll 4
  for (int rep = 0; rep < 16; rep++){
    int idx = rep * 256 + tid;
    int ni = idx >> 6, fi = idx & 63;
    Wg[((size_t)s * 512 + n0 + ni) * FR + f0 + fi] = f2bf(tg[fi][ni]);
  }
  if (tid < 64){
    float sg = 0.f, sb = 0.f;
    for (int fi = 0; fi < 64; fi++){ sg += tg[fi][tid]; sb += tb[fi][tid]; }
    atomic_add_f(&gW[s * 512 + n0 + tid], sg);
    atomic_add_f(&bW[s * 512 + n0 + tid], sb);
  }
}

__global__ __launch_bounds__(256) void k_w2t(
    const float* __restrict__ W2, const float* __restrict__ U,
    unsigned short* __restrict__ W2t)
{
  __shared__ float t[64][65];
  int n0 = blockIdx.x * 64, k0 = blockIdx.y * 64, s = blockIdx.z;
  float u0 = U[s], u1 = U[4+s], u2 = U[8+s], u3 = U[12+s];
  int tid = threadIdx.x;
  #pragma unroll 4
  for (int rep = 0; rep < 16; rep++){
    int idx = rep * 256 + tid;
    int ki = idx >> 6, ni = idx & 63;
    size_t base = (size_t)(k0 + ki) * 512 + (n0 + ni);
    t[ki][ni] = u0*W2[base] + u1*W2[base + 512*512]
              + u2*W2[base + 2*512*512] + u3*W2[base + 3*512*512];
  }
  __syncthreads();
  #pragma unroll 4
  for (int rep = 0; rep < 16; rep++){
    int idx = rep * 256 + tid;
    int ni = idx >> 6, ki = idx & 63;
    W2t[((size_t)s * 512 + n0 + ni) * 512 + k0 + ki] = f2bf(t[ki][ni]);
  }
}

__global__ void k_w3(const float* __restrict__ W3, const float* __restrict__ U,
                     float* __restrict__ W3s)
{
  int idx = blockIdx.x * 256 + threadIdx.x;
  if (idx < 4 * 512){
    int s = idx >> 9, k = idx & 511;
    W3s[idx] = U[s]*W3[k] + U[4+s]*W3[512+k] + U[8+s]*W3[2*512+k] + U[12+s]*W3[3*512+k];
  }
}

// ---------------- GEMM template (128x128 tile, BK=64, bf16 MFMA) ----------------
template<int EPI, int NSPLIT>
__global__ __launch_bounds__(256) void k_gemm(
    const unsigned short* __restrict__ Ag, int lda, int K,
    const unsigned short* __restrict__ Btg,
    const int* __restrict__ list, const int* __restrict__ offs, const int* __restrict__ cnt,
    unsigned short* __restrict__ pout,
    const float* __restrict__ W3s, float* __restrict__ pacc)
{
  __shared__ alignas(16) char smem[32768];
  const int NV = 4 * NSPLIT;
  int b = blockIdx.x;
  int y = (b & 7) + 8 * (b / (8 * NV));
  int v = (b >> 3) % NV;
  int x = v & 3, kh = v >> 2;

  int s = 0, t = y;
  for (; s < 4; s++){
    int nts = (cnt[s] + 127) >> 7;
    if (t < nts) break;
    t -= nts;
  }
  if (s >= 4) return;
  int cntS = cnt[s], offS = offs[s];
  int rt = t, n0 = x * 128;
  int tid = threadIdx.x, w = tid >> 6, lane = tid & 63;
  int wr = w >> 1, wc = w & 1;

  const unsigned short* Bts = Btg + (size_t)s * 512 * K;
  const unsigned short* gA[4];
  const unsigned short* gB[4];
  char* lA[4];
  char* lB[4];
  #pragma unroll
  for (int it = 0; it < 4; it++){
    int g = it * 4 + w;
    int idx = g * 64 + lane;
    int row = idx >> 3, ch = idx & 7;
    int cg = ch ^ (row & 7);
    int gr = rt * 128 + row; gr = gr < cntS ? gr : cntS - 1;
    int atom = list[offS + gr];
    gA[it] = Ag + (size_t)atom * lda + cg * 8;
    lA[it] = smem + g * 1024;
    gB[it] = Bts + (size_t)(n0 + row) * K + cg * 8;
    lB[it] = smem + 16384 + g * 1024;
  }

  int hi = lane >> 4, lo = lane & 15;
  f32x4 acc[4][4];
  #pragma unroll
  for (int mi = 0; mi < 4; mi++)
    #pragma unroll
    for (int ni = 0; ni < 4; ni++)
      #pragma unroll
      for (int r = 0; r < 4; r++) acc[mi][ni][r] = 0.f;

  int abase[4], a7[4], bbase[4], b7[4];
  #pragma unroll
  for (int mi = 0; mi < 4; mi++){ int row = wr*64 + mi*16 + lo; abase[mi] = row*128; a7[mi] = row & 7; }
  #pragma unroll
  for (int ni = 0; ni < 4; ni++){ int row = wc*64 + ni*16 + lo; bbase[ni] = 16384 + row*128; b7[ni] = row & 7; }

  int nk = K / 64;
  int k0 = ((nk * kh) / NSPLIT) * 64;
  int k1 = ((nk * (kh + 1)) / NSPLIT) * 64;

  for (int kt = k0; kt < k1; kt += 64){
    #pragma unroll
    for (int it = 0; it < 4; it++) gload16(gA[it] + kt, lA[it]);
    #pragma unroll
    for (int it = 0; it < 4; it++) gload16(gB[it] + kt, lB[it]);
    __syncthreads();
    #pragma unroll
    for (int kk = 0; kk < 2; kk++){
      bf16x8 af[4], bfr[4];
      #pragma unroll
      for (int mi = 0; mi < 4; mi++)
        af[mi] = *(const bf16x8*)(smem + abase[mi] + (((kk*4 + hi) ^ a7[mi]) << 4));
      #pragma unroll
      for (int ni = 0; ni < 4; ni++)
        bfr[ni] = *(const bf16x8*)(smem + bbase[ni] + (((kk*4 + hi) ^ b7[ni]) << 4));
      #pragma unroll
      for (int mi = 0; mi < 4; mi++)
        #pragma unroll
        for (int ni = 0; ni < 4; ni++)
          acc[mi][ni] = __builtin_amdgcn_mfma_f32_16x16x32_bf16(af[mi], bfr[ni], acc[mi][ni], 0, 0, 0);
    }
    __syncthreads();
  }

  int gn[4];
  #pragma unroll
  for (int ni = 0; ni < 4; ni++) gn[ni] = n0 + wc*64 + ni*16 + lo;

  if (EPI == 0){
    #pragma unroll
    for (int mi = 0; mi < 4; mi++){
      #pragma unroll
      for (int j = 0; j < 4; j++){
        int gr = rt*128 + wr*64 + mi*16 + hi*4 + j;
        if (gr < cntS){
          int atom = list[offS + gr];
          #pragma unroll
          for (int ni = 0; ni < 4; ni++)
            pout[((size_t)kh * NA + atom) * 512 + gn[ni]] = f2bf(acc[mi][ni][j]);
        }
      }
    }
  } else {
    float w3v[4];
    #pragma unroll
    for (int ni = 0; ni < 4; ni++) w3v[ni] = W3s[s * 512 + gn[ni]];
    float* pslot = pacc + (size_t)(x * 2 + wc) * NA;
    #pragma unroll
    for (int mi = 0; mi < 4; mi++){
      #pragma unroll
      for (int j = 0; j < 4; j++){
        int gr = rt*128 + wr*64 + mi*16 + hi*4 + j;
        if (gr < cntS){
          int atom = list[offS + gr];
          float pdot = 0.f;
          #pragma unroll
          for (int ni = 0; ni < 4; ni++)
            pdot += silu(acc[mi][ni][j]) * w3v[ni];
          pdot += __shfl_xor(pdot, 1, 16);
          pdot += __shfl_xor(pdot, 2, 16);
          pdot += __shfl_xor(pdot, 4, 16);
          pdot += __shfl_xor(pdot, 8, 16);
          if (lo == 0) pslot[atom] = pdot;
        }
      }
    }
  }
}

// ---------------- epilogue: combine split-K partials + LN-affine + silu -> h1 ---------
__global__ __launch_bounds__(256) void k_epi(
    const unsigned short* __restrict__ pbuf, const float* __restrict__ stats,
    const float* __restrict__ gW, const float* __restrict__ bW,
    const int* __restrict__ numbers, unsigned short* __restrict__ h1)
{
  int w = threadIdx.x >> 6, lane = threadIdx.x & 63;
  int atom = blockIdx.x * 4 + w;
  int s = numbers[atom];
  float mean = stats[2*atom], rstd = stats[2*atom+1];
  int c0 = lane * 8;
  u16x8 a0 = *reinterpret_cast<const u16x8*>(pbuf + (size_t)atom * 512 + c0);
  u16x8 a1 = *reinterpret_cast<const u16x8*>(pbuf + (size_t)(NA + atom) * 512 + c0);
  unsigned short o[8];
  #pragma unroll
  for (int j = 0; j < 8; j++){
    int c = c0 + j;
    float acc = bf2f(a0[j]) + bf2f(a1[j]);
    float vv = rstd * acc + bW[s*512 + c] - mean * rstd * gW[s*512 + c];
    o[j] = f2bf(silu(vv));
  }
  *reinterpret_cast<u16x8*>(h1 + (size_t)atom * 512 + c0) = *(const u16x8*)o;
}

// ---------------- final: sum 8 pacc partials/atom, wave-uniform molecule atomic -------
__global__ __launch_bounds__(256) void k_final2(
    const float* __restrict__ pacc, const int* __restrict__ numbers,
    const int* __restrict__ batch, const float* __restrict__ Wc,
    float* __restrict__ molOut)
{
  int atom = blockIdx.x * 256 + threadIdx.x;
  int lane = threadIdx.x & 63;
  float sum = 0.f;
  #pragma unroll
  for (int p = 0; p < 8; p++) sum += pacc[(size_t)p * NA + atom];
  float val = sum * (1.f / 128.f) + Wc[numbers[atom]];
  int mol = batch[atom];
  int m0 = __shfl(mol, 0, 64);
  int m63 = __shfl(mol, 63, 64);
  if (m0 == m63){
    #pragma unroll
    for (int m = 32; m; m >>= 1) val += __shfl_xor(val, m, 64);
    if (lane == 0) atomic_add_f(&molOut[mol], val);
  } else {
    atomic_add_f(&molOut[mol], val);
  }
}

extern "C" void kernel_launch(void* const* d_in, const int* in_sizes, int n_in,
                              void* d_out, int out_size, void* d_ws, size_t ws_size,
                              hipStream_t stream)
{
  const float* pos     = (const float*)d_in[0];
  const float* cells   = (const float*)d_in[1];
  const int*   numbers = (const int*)d_in[2];
  const int*   ei      = (const int*)d_in[3];
  const float* eoff    = (const float*)d_in[4];
  const int*   batch   = (const int*)d_in[5];
  const float* U       = (const float*)d_in[6];
  const float* gamma   = (const float*)d_in[7];
  const float* beta    = (const float*)d_in[8];
  const float* W1      = (const float*)d_in[9];
  const float* W2      = (const float*)d_in[10];
  const float* W3      = (const float*)d_in[11];
  const float* Wc      = (const float*)d_in[12];
  float* out = (float*)d_out;

  char* ws = (char*)d_ws;
  size_t off = 0;
  auto alloc = [&](size_t bytes) -> void* {
    void* p = ws + off;
    off += (bytes + 255) & ~(size_t)255;
    return p;
  };
  unsigned short* ps   = (unsigned short*)alloc((size_t)NA * FR * 2);      // 78 MB
  unsigned short* pbuf = (unsigned short*)alloc((size_t)2 * NA * 512 * 2); // 32 MB
  float* stats         = (float*)alloc((size_t)NA * 2 * 4);
  unsigned short* Wg1  = (unsigned short*)alloc((size_t)4 * 512 * FR * 2); // 10.2 MB
  float* gW            = (float*)alloc(4 * 512 * 4);
  float* bW            = (float*)alloc(4 * 512 * 4);
  unsigned short* W2t  = (unsigned short*)alloc((size_t)4 * 512 * 512 * 2);
  float* W3s           = (float*)alloc(4 * 512 * 4);
  unsigned short* h1   = (unsigned short*)alloc((size_t)NA * 512 * 2);
  float* pacc          = (float*)alloc((size_t)8 * NA * 4);                // 512 KB
  int* list            = (int*)alloc(NA * 4);
  int* perm            = (int*)alloc((size_t)NE * 4);
  int* startsK         = (int*)alloc((65536 + 1) * 4);
  int* cnt64k          = (int*)alloc(65536 * 4);
  int* cursor64k       = (int*)alloc(65536 * 4);
  int* bsum            = (int*)alloc(256 * 4);
  int* boff            = (int*)alloc(256 * 4);
  int* bhist           = (int*)alloc(64 * 4 * 4);
  int* boffs           = (int*)alloc(64 * 4 * 4);
  int* ints            = (int*)alloc(64);
  int* cnt = ints; int* offs = ints + 8;

  hipMemsetAsync(cnt64k, 0, 65536 * 4, stream);
  hipMemsetAsync(gW, 0, 4 * 512 * 4, stream);
  hipMemsetAsync(bW, 0, 4 * 512 * 4, stream);
  hipMemsetAsync(out, 0, (size_t)out_size * 4, stream);

  // edge counting sort by (recv, sender-species)
  k_hist<<<NE / 256, 256, 0, stream>>>(ei, numbers, cnt64k);
  k_scanA<<<256, 256, 0, stream>>>(cnt64k, bsum);
  k_scanB<<<1, 256, 0, stream>>>(bsum, boff, startsK);
  k_scanC<<<256, 256, 0, stream>>>(cnt64k, boff, startsK, cursor64k);
  k_sortperm<<<NE / 256, 256, 0, stream>>>(ei, numbers, cursor64k, perm);

  // atom species grouping: contention-free stable counting sort (4 bins)
  k_acount<<<NA / 256, 256, 0, stream>>>(numbers, bhist);
  k_aoffs<<<1, 64, 0, stream>>>(bhist, boffs, ints);
  k_aplace<<<NA / 256, 256, 0, stream>>>(numbers, boffs, list);

  // fused edge-accumulate + U-mix + folded power spectrum + LN stats
  k_atom<<<NA, 384, 0, stream>>>(pos, cells, ei, eoff, batch, startsK, perm, U, ps, stats);

  // weight prep (folded K = 2496)
  k_wg1<<<dim3(8, 39, 4), 256, 0, stream>>>(W1, U, gamma, beta, Wg1, gW, bW);
  k_w2t<<<dim3(8, 8, 4), 256, 0, stream>>>(W2, U, W2t);
  k_w3<<<8, 256, 0, stream>>>(W3, U, W3s);

  // GEMM1 split-K=2 (K=2496), then LN+silu epilogue
  k_gemm<0, 2><<<1088, 256, 0, stream>>>(ps, FR, FR, Wg1, list, offs, cnt,
                                         pbuf, nullptr, nullptr);
  k_epi<<<NA / 4, 256, 0, stream>>>(pbuf, stats, gW, bW, numbers, h1);

  // GEMM2 with fused silu + W3 dot -> per-atom partials (atomic-free)
  k_gemm<2, 1><<<544, 256, 0, stream>>>(h1, 512, 512, W2t, list, offs, cnt,
                                        nullptr, W3s, pacc);
  k_final2<<<NA / 256, 256, 0, stream>>>(pacc, numbers, batch, Wc, out);
}